// Round 2
// baseline (15714.284 us; speedup 1.0000x reference)
//
#include <hip/hip_runtime.h>
#include <hip/hip_fp16.h>
#include <math.h>

#define NNODES 262144   // total nodes
#define NNPG   1024     // nodes per graph
#define NGRAPH 256      // graphs
#define INCH   32       // in channels
#define HD     128      // hidden
#define CHQ    32       // quarter-channel block
#define MAXN   8
#define NEDGE  2097152

__device__ __forceinline__ float selu_f(float v){
    const float alpha = 1.6732632423543772f;
    const float scale = 1.0507009873554805f;
    return v > 0.f ? scale * v : scale * alpha * expm1f(v);
}

// ---------------- degree (int atomics) / dinv ----------------
__global__ void k_deg(const int* __restrict__ dst, int* __restrict__ deg){
    int e = blockIdx.x * blockDim.x + threadIdx.x;
    if (e < NEDGE) atomicAdd(&deg[dst[e]], 1);
}

__global__ void k_dinv(float* __restrict__ dinv){
    int i = blockIdx.x * blockDim.x + threadIdx.x;
    if (i < NNODES){
        int d = ((const int*)dinv)[i];
        dinv[i] = rsqrtf((float)d + 1.0f);
    }
}

// ---------------- layer-1 GEMM: x(f32)[N,32] @ W1 -> B0(f16)[N,128] ----------------
__global__ __launch_bounds__(128) void k_gemm_l1(const float* __restrict__ X,
        const float* __restrict__ W, __half* __restrict__ Y){
    __shared__ float xs[16 * INCH];
    const int r0 = blockIdx.x * 16;
    const int c = threadIdx.x;
    ((float4*)xs)[c] = ((const float4*)(X + (size_t)r0 * INCH))[c];
    __syncthreads();
    float acc[16];
    #pragma unroll
    for (int r = 0; r < 16; ++r) acc[r] = 0.f;
    for (int k = 0; k < INCH; ++k){
        float w = W[k * HD + c];
        #pragma unroll
        for (int r = 0; r < 16; ++r) acc[r] += xs[r * INCH + k] * w;
    }
    #pragma unroll
    for (int r = 0; r < 16; ++r) Y[(size_t)(r0 + r) * HD + c] = __float2half(acc[r]);
}

// ---------------- layer-2 GEMM in-place: B0(f16)[N,128] @ W2 -> B0 ----------------
// Safe: each block stages ONLY its own 16 rows to LDS before overwriting them.
__global__ __launch_bounds__(128) void k_gemm_l2(__half* X, const float* __restrict__ W){
    __shared__ float xs[16 * HD];   // 8 KB
    const int r0 = blockIdx.x * 16;
    const int tid = threadIdx.x;
    const uint4* xsrc = (const uint4*)(X + (size_t)r0 * HD);
    for (int idx = tid; idx < 256; idx += 128){
        uint4 u = xsrc[idx];
        const __half2* hp = (const __half2*)&u;
        #pragma unroll
        for (int j = 0; j < 4; ++j){
            float2 f = __half22float2(hp[j]);
            xs[idx * 8 + 2*j]     = f.x;
            xs[idx * 8 + 2*j + 1] = f.y;
        }
    }
    __syncthreads();
    const int c = tid;
    float acc[16];
    #pragma unroll
    for (int r = 0; r < 16; ++r) acc[r] = 0.f;
    for (int k = 0; k < HD; ++k){
        float w = W[k * HD + c];
        #pragma unroll
        for (int r = 0; r < 16; ++r) acc[r] += xs[r * HD + k] * w;
    }
    #pragma unroll
    for (int r = 0; r < 16; ++r) X[(size_t)(r0 + r) * HD + c] = __float2half(acc[r]);
}

// ---------------- K/V quarter GEMM: B0(f16)[N,128] @ W[:,off:off+32] + b -> Y(f16)[N,32] ----
__global__ __launch_bounds__(128) void k_gemm_kv(const __half* __restrict__ X,
        const float* __restrict__ W, const float* __restrict__ bias,
        __half* __restrict__ Y, int off){
    __shared__ float xs[16 * HD];
    const int r0 = blockIdx.x * 16;
    const int tid = threadIdx.x;
    const uint4* xsrc = (const uint4*)(X + (size_t)r0 * HD);
    for (int idx = tid; idx < 256; idx += 128){
        uint4 u = xsrc[idx];
        const __half2* hp = (const __half2*)&u;
        #pragma unroll
        for (int j = 0; j < 4; ++j){
            float2 f = __half22float2(hp[j]);
            xs[idx * 8 + 2*j]     = f.x;
            xs[idx * 8 + 2*j + 1] = f.y;
        }
    }
    __syncthreads();
    const int c  = tid & 31;
    const int rg = tid >> 5;   // 0..3, 4 rows each
    float b0 = bias[off + c];
    float acc[4];
    #pragma unroll
    for (int r = 0; r < 4; ++r) acc[r] = b0;
    for (int k = 0; k < HD; ++k){
        float w = W[k * HD + off + c];
        #pragma unroll
        for (int r = 0; r < 4; ++r) acc[r] += xs[(rg*4 + r) * HD + k] * w;
    }
    #pragma unroll
    for (int r = 0; r < 4; ++r)
        Y[(size_t)(r0 + rg*4 + r) * CHQ + c] = __float2half(acc[r]);
}

// ---------------- agg init: B1(f32)[N,32] = xw[:,off:off+32] * dinv^2 ----------------
__global__ void k_agginit(const __half* __restrict__ B0, const float* __restrict__ dinv,
                          float* __restrict__ B1, int off){
    int i2 = blockIdx.x * blockDim.x + threadIdx.x;   // over N*16 (half2 units)
    if (i2 >= NNODES * 16) return;
    int node = i2 >> 4, c2 = i2 & 15;
    float dd = dinv[node]; dd *= dd;
    float2 f = __half22float2(((const __half2*)B0)[(size_t)node * 64 + off/2 + c2]);
    ((float2*)B1)[(size_t)node * 16 + c2] = make_float2(f.x * dd, f.y * dd);
}

// ---------------- edge scatter: B1[dst,:] += xw[src,off:off+32] * dinv[s]*dinv[d] ----
__global__ void k_scatter(const int* __restrict__ src, const int* __restrict__ dst,
                          const float* __restrict__ dinv, const __half* __restrict__ B0,
                          float* __restrict__ B1, int off){
    int t = blockIdx.x * blockDim.x + threadIdx.x;   // NEDGE*4 threads
    int e = t >> 2;
    if (e >= NEDGE) return;
    int lane = t & 3;
    int s = src[e], d = dst[e];
    float norm = dinv[s] * dinv[d];
    const uint4 u = *(const uint4*)((const __half2*)B0 + (size_t)s * 64 + off/2 + lane*4);
    const __half2* hv = (const __half2*)&u;
    float* ap = B1 + (size_t)d * CHQ + lane * 8;
    #pragma unroll
    for (int j = 0; j < 4; ++j){
        float2 f = __half22float2(hv[j]);
        atomicAdd(ap + 2*j,     f.x * norm);
        atomicAdd(ap + 2*j + 1, f.y * norm);
    }
}

// ---------------- h[:,off:off+32] = selu(B1 + bias) (writes into B0) ----------------
__global__ void k_selubias(const float* __restrict__ B1, const float* __restrict__ bias,
                           __half* __restrict__ B0, int off){
    int i2 = blockIdx.x * blockDim.x + threadIdx.x;   // N*16
    if (i2 >= NNODES * 16) return;
    int node = i2 >> 4, c2 = i2 & 15;
    float2 f = ((const float2*)B1)[(size_t)node * 16 + c2];
    int ch = off + 2 * c2;
    f.x = selu_f(f.x + bias[ch]);
    f.y = selu_f(f.y + bias[ch + 1]);
    ((__half2*)B0)[(size_t)node * 64 + off/2 + c2] = __floats2half2_rn(f.x, f.y);
}

// ---------------- per-graph masked-node selection + shuffle ----------------
__global__ void k_qnode(const float* __restrict__ x, const int* __restrict__ shuf,
                        int* __restrict__ qnode){
    int b = blockIdx.x;
    int lane = threadIdx.x;   // 64
    __shared__ int list[MAXN];
    int localIdx[16];
    int cnt = 0;
    #pragma unroll
    for (int j = 0; j < 16; ++j){
        int node = lane * 16 + j;
        float m = x[(size_t)(b * NNPG + node) * INCH + (INCH - 3)];
        if (m > 0.5f){ if (cnt < 16) localIdx[cnt] = node; cnt++; }
    }
    int pref = cnt;
    #pragma unroll
    for (int off = 1; off < 64; off <<= 1){
        int v = __shfl_up(pref, off);
        if (lane >= off) pref += v;
    }
    pref -= cnt;
    for (int t = 0; t < cnt; ++t){
        int pos = pref + t;
        if (pos < MAXN) list[pos] = localIdx[t];
    }
    __syncthreads();
    if (lane < MAXN){
        int sidx = shuf[b * MAXN + lane];
        qnode[b * MAXN + lane] = b * NNPG + list[sidx];
    }
}

// ---------------- Q = (h2[qnode] @ Wq + bq) / sqrt(H)  (f32) ----------------
__global__ __launch_bounds__(128) void k_qgemm(const __half* __restrict__ h, const int* __restrict__ qnode,
        const float* __restrict__ Wq, const float* __restrict__ bq, float* __restrict__ Q){
    __shared__ float hs[HD];
    int row = blockIdx.x;
    int c = threadIdx.x;
    int node = qnode[row];
    if (c < 64){
        float2 f = __half22float2(((const __half2*)h)[(size_t)node * 64 + c]);
        hs[2*c] = f.x; hs[2*c + 1] = f.y;
    }
    __syncthreads();
    float acc = bq[c];
    for (int k = 0; k < HD; ++k) acc += hs[k] * Wq[k * HD + c];
    Q[row * HD + c] = acc * 0.08838834764831845f;   // fold 1/sqrt(128)
}

// ---------------- scores[bi][k] (+)= Q[bi,off:off+32] . Kq[b*1024+k, :] ----------------
template<bool FIRST>
__global__ __launch_bounds__(256) void k_scores(const float* __restrict__ Q, const __half* __restrict__ Kq,
        float* __restrict__ scores, int off){
    int bi = blockIdx.x, b = bi >> 3;
    __shared__ float qs[CHQ];
    int tid = threadIdx.x;
    if (tid < CHQ) qs[tid] = Q[bi * HD + off + tid];
    __syncthreads();
    for (int k = tid; k < NNPG; k += 256){
        const uint4* kr = (const uint4*)(Kq + ((size_t)b * NNPG + k) * CHQ);
        float acc = 0.f;
        #pragma unroll
        for (int m = 0; m < 4; ++m){   // 4 x uint4 = 32 halfs
            uint4 u = kr[m];
            const __half2* hp = (const __half2*)&u;
            #pragma unroll
            for (int j = 0; j < 4; ++j){
                float2 f = __half22float2(hp[j]);
                acc += qs[m*8 + 2*j] * f.x + qs[m*8 + 2*j + 1] * f.y;
            }
        }
        float* sp = scores + (size_t)bi * NNPG + k;
        if (FIRST) *sp = acc; else *sp += acc;
    }
}

// ---------------- softmax in-place per (b,i) row of 1024 ----------------
__global__ __launch_bounds__(256) void k_softmax(float* __restrict__ scores){
    int bi = blockIdx.x;
    int tid = threadIdx.x;
    float* row = scores + (size_t)bi * NNPG;
    __shared__ float red[4];
    float v[4], lmax = -1e30f;
    #pragma unroll
    for (int j = 0; j < 4; ++j){ v[j] = row[tid + j * 256]; lmax = fmaxf(lmax, v[j]); }
    #pragma unroll
    for (int off = 32; off; off >>= 1) lmax = fmaxf(lmax, __shfl_down(lmax, off));
    if ((tid & 63) == 0) red[tid >> 6] = lmax;
    __syncthreads();
    float rmax = fmaxf(fmaxf(red[0], red[1]), fmaxf(red[2], red[3]));
    float lsum = 0.f;
    #pragma unroll
    for (int j = 0; j < 4; ++j){ v[j] = expf(v[j] - rmax); lsum += v[j]; }
    #pragma unroll
    for (int off = 32; off; off >>= 1) lsum += __shfl_down(lsum, off);
    __syncthreads();
    if ((tid & 63) == 0) red[tid >> 6] = lsum;
    __syncthreads();
    float inv = 1.0f / (red[0] + red[1] + red[2] + red[3]);
    #pragma unroll
    for (int j = 0; j < 4; ++j) row[tid + j * 256] = v[j] * inv;
}

// ---------------- PV: pvout[b,i,off:off+32] = sum_k attn[b,i,k] * Vq[b*1024+k,:] ----
__global__ __launch_bounds__(256) void k_pv(const float* __restrict__ attn, const __half* __restrict__ Vq,
        float* __restrict__ pvout, int off){
    int b = blockIdx.x;
    int tid = threadIdx.x;
    __shared__ float at[MAXN * NNPG];   // 32 KB
    const float* arow = attn + (size_t)b * MAXN * NNPG;
    for (int idx = tid; idx < MAXN * NNPG / 4; idx += 256)
        ((float4*)at)[idx] = ((const float4*)arow)[idx];
    __syncthreads();
    int c = tid & 31;
    int i = tid >> 5;    // 0..7 — one query slot per 32-thread group
    const __half* vb = Vq + (size_t)b * NNPG * CHQ + c;
    float acc = 0.f;
    for (int k = 0; k < NNPG; ++k){
        float v = __half2float(vb[(size_t)k * CHQ]);
        acc += at[i * NNPG + k] * v;
    }
    pvout[(size_t)(b * MAXN + i) * HD + off + c] = acc;
}

// ---------------- tail: Wo+bo+selu then Wfc+bfc -> out[b][8] ----------------
__global__ __launch_bounds__(256) void k_tail(const float* __restrict__ pvout,
        const float* __restrict__ Wo, const float* __restrict__ bo,
        const float* __restrict__ Wfc, const float* __restrict__ bfc,
        float* __restrict__ out){
    int b = blockIdx.x;
    int tid = threadIdx.x;
    __shared__ float pv[MAXN * HD];
    __shared__ float sol[MAXN * HD];
    __shared__ float red[64];
    for (int idx = tid; idx < MAXN * HD / 4; idx += 256)
        ((float4*)pv)[idx] = ((const float4*)(pvout + (size_t)b * MAXN * HD))[idx];
    __syncthreads();
    int c = tid & 127;
    int grp = tid >> 7;   // 0/1 -> 4 query slots each
    float bb = bo[c];
    float acc[4];
    #pragma unroll
    for (int j = 0; j < 4; ++j) acc[j] = bb;
    for (int k = 0; k < HD; ++k){
        float w = Wo[k * HD + c];
        #pragma unroll
        for (int j = 0; j < 4; ++j) acc[j] += pv[(grp*4 + j) * HD + k] * w;
    }
    #pragma unroll
    for (int j = 0; j < 4; ++j) sol[(grp*4 + j) * HD + c] = selu_f(acc[j]);
    __syncthreads();
    if (tid < 64){
        int j = tid & 7;
        int part = tid >> 3;
        float p = 0.f;
        for (int m = part * 128; m < part * 128 + 128; ++m) p += sol[m] * Wfc[m * MAXN + j];
        red[tid] = p;
    }
    __syncthreads();
    if (tid < MAXN){
        float s = bfc[tid];
        #pragma unroll
        for (int part = 0; part < 8; ++part) s += red[part * 8 + tid];
        out[b * MAXN + tid] = s;
    }
}

extern "C" void kernel_launch(void* const* d_in, const int* in_sizes, int n_in,
                              void* d_out, int out_size, void* d_ws, size_t ws_size,
                              hipStream_t stream) {
    const float* x    = (const float*)d_in[0];
    const int*   edge = (const int*)d_in[1];
    const int*   shuf = (const int*)d_in[2];
    const float* W1   = (const float*)d_in[3];
    const float* b1   = (const float*)d_in[4];
    const float* W2   = (const float*)d_in[5];
    const float* b2   = (const float*)d_in[6];
    const float* Wq   = (const float*)d_in[7];
    const float* bq   = (const float*)d_in[8];
    const float* Wk   = (const float*)d_in[9];
    const float* bk   = (const float*)d_in[10];
    const float* Wv   = (const float*)d_in[11];
    const float* bv   = (const float*)d_in[12];
    const float* Wo   = (const float*)d_in[13];
    const float* bo   = (const float*)d_in[14];
    const float* Wfc  = (const float*)d_in[15];
    const float* bfc  = (const float*)d_in[16];
    float* out = (float*)d_out;

    // workspace layout — total ~107 MiB
    char* w = (char*)d_ws;
    __half* B0    = (__half*)w;  w += (size_t)NNODES * HD * sizeof(__half);   // 64 MiB
    float*  B1    = (float*)w;   w += (size_t)NNODES * CHQ * sizeof(float);   // 32 MiB
    float*  dinv  = (float*)w;   w += (size_t)NNODES * sizeof(float);         // 1 MiB
    float*  scores= (float*)w;   w += (size_t)NGRAPH * MAXN * NNPG * sizeof(float); // 8 MiB
    float*  Qb    = (float*)w;   w += (size_t)NGRAPH * MAXN * HD * sizeof(float);   // 1 MiB
    float*  pvout = (float*)w;   w += (size_t)NGRAPH * MAXN * HD * sizeof(float);   // 1 MiB
    int*    qnode = (int*)w;     w += (size_t)NGRAPH * MAXN * sizeof(int);
    size_t need = (size_t)(w - (char*)d_ws);
    if (ws_size < need) return;

    const int* srcp = edge;
    const int* dstp = edge + NEDGE;

    hipMemsetAsync(dinv, 0, NNODES * sizeof(int), stream);
    k_deg<<<NEDGE / 256, 256, 0, stream>>>(dstp, (int*)dinv);
    k_dinv<<<NNODES / 256, 256, 0, stream>>>(dinv);

    const int qBlocks = (NNODES * 16) / 256;     // 16384 (half2-granular elementwise)

    // ---- layer 1 ----
    k_gemm_l1<<<NNODES / 16, 128, 0, stream>>>(x, W1, B0);
    for (int off = 0; off < HD; off += CHQ){
        k_agginit<<<qBlocks, 256, 0, stream>>>(B0, dinv, B1, off);
        k_scatter<<<NEDGE * 4 / 256, 256, 0, stream>>>(srcp, dstp, dinv, B0, B1, off);
        k_selubias<<<qBlocks, 256, 0, stream>>>(B1, b1, B0, off);
    }
    // ---- layer 2 (in-place xw) ----
    k_gemm_l2<<<NNODES / 16, 128, 0, stream>>>(B0, W2);
    for (int off = 0; off < HD; off += CHQ){
        k_agginit<<<qBlocks, 256, 0, stream>>>(B0, dinv, B1, off);
        k_scatter<<<NEDGE * 4 / 256, 256, 0, stream>>>(srcp, dstp, dinv, B0, B1, off);
        k_selubias<<<qBlocks, 256, 0, stream>>>(B1, b2, B0, off);
    }
    // ---- attention ----
    k_qnode<<<NGRAPH, 64, 0, stream>>>(x, shuf, qnode);
    k_qgemm<<<NGRAPH * MAXN, 128, 0, stream>>>(B0, qnode, Wq, bq, Qb);

    k_gemm_kv<<<NNODES / 16, 128, 0, stream>>>(B0, Wk, bk, B1 /*as f16*/ ? (__half*)B1 : (__half*)B1, 0);
    k_scores<true><<<NGRAPH * MAXN, 256, 0, stream>>>(Qb, (const __half*)B1, scores, 0);
    for (int off = CHQ; off < HD; off += CHQ){
        k_gemm_kv<<<NNODES / 16, 128, 0, stream>>>(B0, Wk, bk, (__half*)B1, off);
        k_scores<false><<<NGRAPH * MAXN, 256, 0, stream>>>(Qb, (const __half*)B1, scores, off);
    }
    k_softmax<<<NGRAPH * MAXN, 256, 0, stream>>>(scores);
    for (int off = 0; off < HD; off += CHQ){
        k_gemm_kv<<<NNODES / 16, 128, 0, stream>>>(B0, Wv, bv, (__half*)B1, off);
        k_pv<<<NGRAPH, 256, 0, stream>>>(scores, (const __half*)B1, pvout, off);
    }
    k_tail<<<NGRAPH, 256, 0, stream>>>(pvout, Wo, bo, Wfc, bfc, out);
}

// Round 3
// 2337.202 us; speedup vs baseline: 6.7235x; 6.7235x over previous
//
#include <hip/hip_runtime.h>
#include <hip/hip_fp16.h>
#include <math.h>

#define NNODES 262144   // total nodes
#define NNPG   1024     // nodes per graph
#define NGRAPH 256      // graphs
#define INCH   32       // in channels
#define HD     128      // hidden
#define CHQ    32       // quarter-channel block
#define MAXN   8
#define NEDGE  2097152

__device__ __forceinline__ float selu_f(float v){
    const float alpha = 1.6732632423543772f;
    const float scale = 1.0507009873554805f;
    return v > 0.f ? scale * v : scale * alpha * expm1f(v);
}

// ---------------- degree (int atomics) ----------------
__global__ void k_deg(const int* __restrict__ dst, int* __restrict__ deg){
    int e = blockIdx.x * blockDim.x + threadIdx.x;
    if (e < NEDGE) atomicAdd(&deg[dst[e]], 1);
}

__global__ void k_dinv(const int* __restrict__ deg, float* __restrict__ dinv){
    int i = blockIdx.x * blockDim.x + threadIdx.x;
    if (i < NNODES) dinv[i] = rsqrtf((float)deg[i] + 1.0f);
}

// ---------------- exclusive prefix sum of deg[N] -> indptr ----------------
// pass 1: per-block (1024 elems) exclusive scan + block totals
__global__ __launch_bounds__(256) void k_scan1(const int* __restrict__ deg,
        int* __restrict__ indptr, int* __restrict__ bsum){
    int bid = blockIdx.x, tid = threadIdx.x;
    int4 v = ((const int4*)deg)[bid * 256 + tid];
    int s = v.x + v.y + v.z + v.w;
    int lane = tid & 63;
    int p = s;
    #pragma unroll
    for (int off = 1; off < 64; off <<= 1){
        int u = __shfl_up(p, off);
        if (lane >= off) p += u;
    }
    __shared__ int ws[4];
    if (lane == 63) ws[tid >> 6] = p;
    __syncthreads();
    int w = tid >> 6, wo = 0;
    if (w > 0) wo = ws[0];
    if (w > 1) wo += ws[1];
    if (w > 2) wo += ws[2];
    int excl = wo + p - s;
    int base = bid * 1024 + tid * 4;
    indptr[base + 0] = excl;
    indptr[base + 1] = excl + v.x;
    indptr[base + 2] = excl + v.x + v.y;
    indptr[base + 3] = excl + v.x + v.y + v.z;
    if (tid == 255) bsum[bid] = excl + s;
}

// pass 2: exclusive scan of 256 block sums (single block)
__global__ __launch_bounds__(256) void k_scan2(int* __restrict__ bsum){
    int tid = threadIdx.x;
    int v = bsum[tid];
    int lane = tid & 63;
    int p = v;
    #pragma unroll
    for (int off = 1; off < 64; off <<= 1){
        int u = __shfl_up(p, off);
        if (lane >= off) p += u;
    }
    __shared__ int ws[4];
    if (lane == 63) ws[tid >> 6] = p;
    __syncthreads();
    int w = tid >> 6, wo = 0;
    if (w > 0) wo = ws[0];
    if (w > 1) wo += ws[1];
    if (w > 2) wo += ws[2];
    bsum[tid] = wo + p - v;
}

// pass 3: add block offsets; set indptr[N] = NEDGE
__global__ __launch_bounds__(256) void k_scan3(int* __restrict__ indptr,
        const int* __restrict__ bsum){
    int bid = blockIdx.x;
    int off = bsum[bid];
    int4* p = (int4*)indptr + bid * 256 + threadIdx.x;
    int4 v = *p;
    v.x += off; v.y += off; v.z += off; v.w += off;
    *p = v;
    if (bid == 0 && threadIdx.x == 0) indptr[NNODES] = NEDGE;
}

// ---------------- fill CSR: esrc sorted by dst ----------------
__global__ void k_fill(const int* __restrict__ src, const int* __restrict__ dst,
        const int* __restrict__ indptr, int* __restrict__ cursor, int* __restrict__ esrc){
    int e = blockIdx.x * blockDim.x + threadIdx.x;
    if (e < NEDGE){
        int d = dst[e];
        int pos = indptr[d] + atomicAdd(&cursor[d], 1);
        esrc[pos] = src[e];
    }
}

// ---------------- layer-1 GEMM: x(f32)[N,32] @ W1 -> B0(f16)[N,128] ----------------
__global__ __launch_bounds__(128) void k_gemm_l1(const float* __restrict__ X,
        const float* __restrict__ W, __half* __restrict__ Y){
    __shared__ float xs[16 * INCH];
    const int r0 = blockIdx.x * 16;
    const int c = threadIdx.x;
    ((float4*)xs)[c] = ((const float4*)(X + (size_t)r0 * INCH))[c];
    __syncthreads();
    float acc[16];
    #pragma unroll
    for (int r = 0; r < 16; ++r) acc[r] = 0.f;
    for (int k = 0; k < INCH; ++k){
        float w = W[k * HD + c];
        #pragma unroll
        for (int r = 0; r < 16; ++r) acc[r] += xs[r * INCH + k] * w;
    }
    #pragma unroll
    for (int r = 0; r < 16; ++r) Y[(size_t)(r0 + r) * HD + c] = __float2half(acc[r]);
}

// ---------------- layer-2 GEMM in-place: B0(f16)[N,128] @ W2 -> B0 ----------------
__global__ __launch_bounds__(128) void k_gemm_l2(__half* X, const float* __restrict__ W){
    __shared__ float xs[16 * HD];
    const int r0 = blockIdx.x * 16;
    const int tid = threadIdx.x;
    const uint4* xsrc = (const uint4*)(X + (size_t)r0 * HD);
    for (int idx = tid; idx < 256; idx += 128){
        uint4 u = xsrc[idx];
        const __half2* hp = (const __half2*)&u;
        #pragma unroll
        for (int j = 0; j < 4; ++j){
            float2 f = __half22float2(hp[j]);
            xs[idx * 8 + 2*j]     = f.x;
            xs[idx * 8 + 2*j + 1] = f.y;
        }
    }
    __syncthreads();
    const int c = tid;
    float acc[16];
    #pragma unroll
    for (int r = 0; r < 16; ++r) acc[r] = 0.f;
    for (int k = 0; k < HD; ++k){
        float w = W[k * HD + c];
        #pragma unroll
        for (int r = 0; r < 16; ++r) acc[r] += xs[r * HD + k] * w;
    }
    #pragma unroll
    for (int r = 0; r < 16; ++r) X[(size_t)(r0 + r) * HD + c] = __float2half(acc[r]);
}

// ---------------- copy quarter: B1[n,0:32] = B0[n,off:off+32] ----------------
__global__ void k_copyq(const __half* __restrict__ B0, __half* __restrict__ B1, int off){
    int i = blockIdx.x * blockDim.x + threadIdx.x;   // over N*4 uint4 units
    if (i >= NNODES * 4) return;
    int node = i >> 2, c4 = i & 3;
    ((uint4*)B1)[i] = *(const uint4*)((const char*)B0 + (size_t)node * 256 + off * 2 + c4 * 16);
}

// ---------------- fused gather-aggregate + bias + selu ----------------
// 16 threads per node (one half2 of the 32-ch quarter each)
__global__ __launch_bounds__(256) void k_gather(const int* __restrict__ indptr,
        const int* __restrict__ esrc, const float* __restrict__ dinv,
        const __half* __restrict__ xwq, const float* __restrict__ bias,
        __half* __restrict__ B0, int off){
    int t = blockIdx.x * blockDim.x + threadIdx.x;
    int node = t >> 4;
    if (node >= NNODES) return;
    int c2 = t & 15;
    float dn = dinv[node];
    int beg = indptr[node], end = indptr[node + 1];
    float2 sf = __half22float2(((const __half2*)xwq)[(size_t)node * 16 + c2]);
    float w0 = dn * dn;
    float ax = sf.x * w0, ay = sf.y * w0;
    for (int j = beg; j < end; ++j){
        int s = esrc[j];
        float norm = dinv[s] * dn;
        float2 f = __half22float2(((const __half2*)xwq)[(size_t)s * 16 + c2]);
        ax += f.x * norm;
        ay += f.y * norm;
    }
    int ch = off + 2 * c2;
    ax = selu_f(ax + bias[ch]);
    ay = selu_f(ay + bias[ch + 1]);
    ((__half2*)B0)[(size_t)node * 64 + off / 2 + c2] = __floats2half2_rn(ax, ay);
}

// ---------------- K/V quarter GEMM: B0(f16)[N,128] @ W[:,off:off+32] + b -> B1(f16)[N,32] ----
__global__ __launch_bounds__(128) void k_gemm_kv(const __half* __restrict__ X,
        const float* __restrict__ W, const float* __restrict__ bias,
        __half* __restrict__ Y, int off){
    __shared__ float xs[16 * HD];
    const int r0 = blockIdx.x * 16;
    const int tid = threadIdx.x;
    const uint4* xsrc = (const uint4*)(X + (size_t)r0 * HD);
    for (int idx = tid; idx < 256; idx += 128){
        uint4 u = xsrc[idx];
        const __half2* hp = (const __half2*)&u;
        #pragma unroll
        for (int j = 0; j < 4; ++j){
            float2 f = __half22float2(hp[j]);
            xs[idx * 8 + 2*j]     = f.x;
            xs[idx * 8 + 2*j + 1] = f.y;
        }
    }
    __syncthreads();
    const int c  = tid & 31;
    const int rg = tid >> 5;
    float b0 = bias[off + c];
    float acc[4];
    #pragma unroll
    for (int r = 0; r < 4; ++r) acc[r] = b0;
    for (int k = 0; k < HD; ++k){
        float w = W[k * HD + off + c];
        #pragma unroll
        for (int r = 0; r < 4; ++r) acc[r] += xs[(rg*4 + r) * HD + k] * w;
    }
    #pragma unroll
    for (int r = 0; r < 4; ++r)
        Y[(size_t)(r0 + rg*4 + r) * CHQ + c] = __float2half(acc[r]);
}

// ---------------- per-graph masked-node selection + shuffle ----------------
__global__ void k_qnode(const float* __restrict__ x, const int* __restrict__ shuf,
                        int* __restrict__ qnode){
    int b = blockIdx.x;
    int lane = threadIdx.x;   // 64
    __shared__ int list[MAXN];
    int localIdx[16];
    int cnt = 0;
    #pragma unroll
    for (int j = 0; j < 16; ++j){
        int node = lane * 16 + j;
        float m = x[(size_t)(b * NNPG + node) * INCH + (INCH - 3)];
        if (m > 0.5f){ if (cnt < 16) localIdx[cnt] = node; cnt++; }
    }
    int pref = cnt;
    #pragma unroll
    for (int off = 1; off < 64; off <<= 1){
        int v = __shfl_up(pref, off);
        if (lane >= off) pref += v;
    }
    pref -= cnt;
    for (int t = 0; t < cnt; ++t){
        int pos = pref + t;
        if (pos < MAXN) list[pos] = localIdx[t];
    }
    __syncthreads();
    if (lane < MAXN){
        int sidx = shuf[b * MAXN + lane];
        qnode[b * MAXN + lane] = b * NNPG + list[sidx];
    }
}

// ---------------- Q = (h2[qnode] @ Wq + bq) / sqrt(H)  (f32) ----------------
__global__ __launch_bounds__(128) void k_qgemm(const __half* __restrict__ h, const int* __restrict__ qnode,
        const float* __restrict__ Wq, const float* __restrict__ bq, float* __restrict__ Q){
    __shared__ float hs[HD];
    int row = blockIdx.x;
    int c = threadIdx.x;
    int node = qnode[row];
    if (c < 64){
        float2 f = __half22float2(((const __half2*)h)[(size_t)node * 64 + c]);
        hs[2*c] = f.x; hs[2*c + 1] = f.y;
    }
    __syncthreads();
    float acc = bq[c];
    for (int k = 0; k < HD; ++k) acc += hs[k] * Wq[k * HD + c];
    Q[row * HD + c] = acc * 0.08838834764831845f;   // fold 1/sqrt(128)
}

// ---------------- scores[bi][k] (+)= Q[bi,off:off+32] . Kq[b*1024+k, :] ----------------
template<bool FIRST>
__global__ __launch_bounds__(256) void k_scores(const float* __restrict__ Q, const __half* __restrict__ Kq,
        float* __restrict__ scores, int off){
    int bi = blockIdx.x, b = bi >> 3;
    __shared__ float qs[CHQ];
    int tid = threadIdx.x;
    if (tid < CHQ) qs[tid] = Q[bi * HD + off + tid];
    __syncthreads();
    for (int k = tid; k < NNPG; k += 256){
        const uint4* kr = (const uint4*)(Kq + ((size_t)b * NNPG + k) * CHQ);
        float acc = 0.f;
        #pragma unroll
        for (int m = 0; m < 4; ++m){
            uint4 u = kr[m];
            const __half2* hp = (const __half2*)&u;
            #pragma unroll
            for (int j = 0; j < 4; ++j){
                float2 f = __half22float2(hp[j]);
                acc += qs[m*8 + 2*j] * f.x + qs[m*8 + 2*j + 1] * f.y;
            }
        }
        float* sp = scores + (size_t)bi * NNPG + k;
        if (FIRST) *sp = acc; else *sp += acc;
    }
}

// ---------------- softmax in-place per (b,i) row of 1024 ----------------
__global__ __launch_bounds__(256) void k_softmax(float* __restrict__ scores){
    int bi = blockIdx.x;
    int tid = threadIdx.x;
    float* row = scores + (size_t)bi * NNPG;
    __shared__ float red[4];
    float v[4], lmax = -1e30f;
    #pragma unroll
    for (int j = 0; j < 4; ++j){ v[j] = row[tid + j * 256]; lmax = fmaxf(lmax, v[j]); }
    #pragma unroll
    for (int off = 32; off; off >>= 1) lmax = fmaxf(lmax, __shfl_down(lmax, off));
    if ((tid & 63) == 0) red[tid >> 6] = lmax;
    __syncthreads();
    float rmax = fmaxf(fmaxf(red[0], red[1]), fmaxf(red[2], red[3]));
    float lsum = 0.f;
    #pragma unroll
    for (int j = 0; j < 4; ++j){ v[j] = expf(v[j] - rmax); lsum += v[j]; }
    #pragma unroll
    for (int off = 32; off; off >>= 1) lsum += __shfl_down(lsum, off);
    __syncthreads();
    if ((tid & 63) == 0) red[tid >> 6] = lsum;
    __syncthreads();
    float inv = 1.0f / (red[0] + red[1] + red[2] + red[3]);
    #pragma unroll
    for (int j = 0; j < 4; ++j) row[tid + j * 256] = v[j] * inv;
}

// ---------------- PV: pvout[b,i,off:off+32] = sum_k attn[b,i,k] * Vq[b*1024+k,:] ----
__global__ __launch_bounds__(256) void k_pv(const float* __restrict__ attn, const __half* __restrict__ Vq,
        float* __restrict__ pvout, int off){
    int b = blockIdx.x;
    int tid = threadIdx.x;
    __shared__ float at[MAXN * NNPG];
    const float* arow = attn + (size_t)b * MAXN * NNPG;
    for (int idx = tid; idx < MAXN * NNPG / 4; idx += 256)
        ((float4*)at)[idx] = ((const float4*)arow)[idx];
    __syncthreads();
    int c = tid & 31;
    int i = tid >> 5;
    const __half* vb = Vq + (size_t)b * NNPG * CHQ + c;
    float acc = 0.f;
    for (int k = 0; k < NNPG; ++k){
        float v = __half2float(vb[(size_t)k * CHQ]);
        acc += at[i * NNPG + k] * v;
    }
    pvout[(size_t)(b * MAXN + i) * HD + off + c] = acc;
}

// ---------------- tail: Wo+bo+selu then Wfc+bfc -> out[b][8] ----------------
__global__ __launch_bounds__(256) void k_tail(const float* __restrict__ pvout,
        const float* __restrict__ Wo, const float* __restrict__ bo,
        const float* __restrict__ Wfc, const float* __restrict__ bfc,
        float* __restrict__ out){
    int b = blockIdx.x;
    int tid = threadIdx.x;
    __shared__ float pv[MAXN * HD];
    __shared__ float sol[MAXN * HD];
    __shared__ float red[64];
    for (int idx = tid; idx < MAXN * HD / 4; idx += 256)
        ((float4*)pv)[idx] = ((const float4*)(pvout + (size_t)b * MAXN * HD))[idx];
    __syncthreads();
    int c = tid & 127;
    int grp = tid >> 7;
    float bb = bo[c];
    float acc[4];
    #pragma unroll
    for (int j = 0; j < 4; ++j) acc[j] = bb;
    for (int k = 0; k < HD; ++k){
        float w = Wo[k * HD + c];
        #pragma unroll
        for (int j = 0; j < 4; ++j) acc[j] += pv[(grp*4 + j) * HD + k] * w;
    }
    #pragma unroll
    for (int j = 0; j < 4; ++j) sol[(grp*4 + j) * HD + c] = selu_f(acc[j]);
    __syncthreads();
    if (tid < 64){
        int j = tid & 7;
        int part = tid >> 3;
        float p = 0.f;
        for (int m = part * 128; m < part * 128 + 128; ++m) p += sol[m] * Wfc[m * MAXN + j];
        red[tid] = p;
    }
    __syncthreads();
    if (tid < MAXN){
        float s = bfc[tid];
        #pragma unroll
        for (int part = 0; part < 8; ++part) s += red[part * 8 + tid];
        out[b * MAXN + tid] = s;
    }
}

extern "C" void kernel_launch(void* const* d_in, const int* in_sizes, int n_in,
                              void* d_out, int out_size, void* d_ws, size_t ws_size,
                              hipStream_t stream) {
    const float* x    = (const float*)d_in[0];
    const int*   edge = (const int*)d_in[1];
    const int*   shuf = (const int*)d_in[2];
    const float* W1   = (const float*)d_in[3];
    const float* b1   = (const float*)d_in[4];
    const float* W2   = (const float*)d_in[5];
    const float* b2   = (const float*)d_in[6];
    const float* Wq   = (const float*)d_in[7];
    const float* bq   = (const float*)d_in[8];
    const float* Wk   = (const float*)d_in[9];
    const float* bk   = (const float*)d_in[10];
    const float* Wv   = (const float*)d_in[11];
    const float* bv   = (const float*)d_in[12];
    const float* Wo   = (const float*)d_in[13];
    const float* bo   = (const float*)d_in[14];
    const float* Wfc  = (const float*)d_in[15];
    const float* bfc  = (const float*)d_in[16];
    float* out = (float*)d_out;

    // workspace layout — ~93 MiB total
    char* w = (char*)d_ws;
    __half* B0    = (__half*)w;  w += (size_t)NNODES * HD * sizeof(__half);    // 64 MiB
    __half* B1    = (__half*)w;  w += (size_t)NNODES * CHQ * sizeof(__half);   // 16 MiB
    float*  dinv  = (float*)w;   w += (size_t)NNODES * sizeof(float);          // 1 MiB
    int*    degcur= (int*)w;     w += (size_t)NNODES * sizeof(int);            // 1 MiB (deg, then cursor)
    int*    indptr= (int*)w;     w += ((size_t)NNODES + 64) * sizeof(int);     // 1 MiB
    int*    bsum  = (int*)w;     w += 256 * sizeof(int);
    char*   U     = w;           w += (size_t)NGRAPH * MAXN * NNPG * sizeof(float); // 8 MiB: esrc ∪ scores
    float*  Qb    = (float*)w;   w += (size_t)NGRAPH * MAXN * HD * sizeof(float);   // 1 MiB
    float*  pvout = (float*)w;   w += (size_t)NGRAPH * MAXN * HD * sizeof(float);   // 1 MiB
    int*    qnode = (int*)w;     w += (size_t)NGRAPH * MAXN * sizeof(int);
    size_t need = (size_t)(w - (char*)d_ws);
    if (ws_size < need) return;

    int*   esrc   = (int*)U;     // used during GNN layers
    float* scores = (float*)U;   // used during attention (after layers)

    const int* srcp = edge;
    const int* dstp = edge + NEDGE;

    // ---- CSR build ----
    hipMemsetAsync(degcur, 0, NNODES * sizeof(int), stream);
    k_deg<<<NEDGE / 256, 256, 0, stream>>>(dstp, degcur);
    k_dinv<<<NNODES / 256, 256, 0, stream>>>(degcur, dinv);
    k_scan1<<<256, 256, 0, stream>>>(degcur, indptr, bsum);
    k_scan2<<<1, 256, 0, stream>>>(bsum);
    k_scan3<<<256, 256, 0, stream>>>(indptr, bsum);
    hipMemsetAsync(degcur, 0, NNODES * sizeof(int), stream);
    k_fill<<<NEDGE / 256, 256, 0, stream>>>(srcp, dstp, indptr, degcur, esrc);

    const int cBlocks = (NNODES * 4) / 256;       // copyq grid
    const int gBlocks = (NNODES * 16) / 256;      // gather grid

    // ---- layer 1: xw1 = x @ W1 (full, into B0), then quarter gathers ----
    k_gemm_l1<<<NNODES / 16, 128, 0, stream>>>(x, W1, B0);
    for (int off = 0; off < HD; off += CHQ){
        k_copyq<<<cBlocks, 256, 0, stream>>>(B0, B1, off);
        k_gather<<<gBlocks, 256, 0, stream>>>(indptr, esrc, dinv, B1, b1, B0, off);
    }
    // ---- layer 2: xw2 = h1 @ W2 (in-place), then quarter gathers ----
    k_gemm_l2<<<NNODES / 16, 128, 0, stream>>>(B0, W2);
    for (int off = 0; off < HD; off += CHQ){
        k_copyq<<<cBlocks, 256, 0, stream>>>(B0, B1, off);
        k_gather<<<gBlocks, 256, 0, stream>>>(indptr, esrc, dinv, B1, b2, B0, off);
    }
    // ---- attention ----
    k_qnode<<<NGRAPH, 64, 0, stream>>>(x, shuf, qnode);
    k_qgemm<<<NGRAPH * MAXN, 128, 0, stream>>>(B0, qnode, Wq, bq, Qb);

    k_gemm_kv<<<NNODES / 16, 128, 0, stream>>>(B0, Wk, bk, B1, 0);
    k_scores<true><<<NGRAPH * MAXN, 256, 0, stream>>>(Qb, B1, scores, 0);
    for (int off = CHQ; off < HD; off += CHQ){
        k_gemm_kv<<<NNODES / 16, 128, 0, stream>>>(B0, Wk, bk, B1, off);
        k_scores<false><<<NGRAPH * MAXN, 256, 0, stream>>>(Qb, B1, scores, off);
    }
    k_softmax<<<NGRAPH * MAXN, 256, 0, stream>>>(scores);
    for (int off = 0; off < HD; off += CHQ){
        k_gemm_kv<<<NNODES / 16, 128, 0, stream>>>(B0, Wv, bv, B1, off);
        k_pv<<<NGRAPH, 256, 0, stream>>>(scores, B1, pvout, off);
    }
    k_tail<<<NGRAPH, 256, 0, stream>>>(pvout, Wo, bo, Wfc, bfc, out);
}

// Round 4
// 1156.634 us; speedup vs baseline: 13.5862x; 2.0207x over previous
//
#include <hip/hip_runtime.h>
#include <hip/hip_fp16.h>
#include <math.h>

#define NNODES 262144   // total nodes
#define NNPG   1024     // nodes per graph
#define NGRAPH 256      // graphs
#define INCH   32       // in channels
#define HD     128      // hidden
#define MAXN   8
#define NEDGE  2097152

using half8  = __attribute__((ext_vector_type(8))) _Float16;
using floatx4 = __attribute__((ext_vector_type(4))) float;

__device__ __forceinline__ float selu_f(float v){
    const float alpha = 1.6732632423543772f;
    const float scale = 1.0507009873554805f;
    return v > 0.f ? scale * v : scale * alpha * expm1f(v);
}

// ---------------- degree / dinv ----------------
__global__ void k_deg(const int* __restrict__ dst, int* __restrict__ deg){
    int e = blockIdx.x * blockDim.x + threadIdx.x;
    if (e < NEDGE) atomicAdd(&deg[dst[e]], 1);
}

__global__ void k_dinv(const int* __restrict__ deg, float* __restrict__ dinv){
    int i = blockIdx.x * blockDim.x + threadIdx.x;
    if (i < NNODES) dinv[i] = rsqrtf((float)deg[i] + 1.0f);
}

// ---------------- prefix sum (3-pass) ----------------
__global__ __launch_bounds__(256) void k_scan1(const int* __restrict__ deg,
        int* __restrict__ indptr, int* __restrict__ bsum){
    int bid = blockIdx.x, tid = threadIdx.x;
    int4 v = ((const int4*)deg)[bid * 256 + tid];
    int s = v.x + v.y + v.z + v.w;
    int lane = tid & 63;
    int p = s;
    #pragma unroll
    for (int off = 1; off < 64; off <<= 1){
        int u = __shfl_up(p, off);
        if (lane >= off) p += u;
    }
    __shared__ int ws[4];
    if (lane == 63) ws[tid >> 6] = p;
    __syncthreads();
    int w = tid >> 6, wo = 0;
    if (w > 0) wo = ws[0];
    if (w > 1) wo += ws[1];
    if (w > 2) wo += ws[2];
    int excl = wo + p - s;
    int base = bid * 1024 + tid * 4;
    indptr[base + 0] = excl;
    indptr[base + 1] = excl + v.x;
    indptr[base + 2] = excl + v.x + v.y;
    indptr[base + 3] = excl + v.x + v.y + v.z;
    if (tid == 255) bsum[bid] = excl + s;
}

__global__ __launch_bounds__(256) void k_scan2(int* __restrict__ bsum){
    int tid = threadIdx.x;
    int v = bsum[tid];
    int lane = tid & 63;
    int p = v;
    #pragma unroll
    for (int off = 1; off < 64; off <<= 1){
        int u = __shfl_up(p, off);
        if (lane >= off) p += u;
    }
    __shared__ int ws[4];
    if (lane == 63) ws[tid >> 6] = p;
    __syncthreads();
    int w = tid >> 6, wo = 0;
    if (w > 0) wo = ws[0];
    if (w > 1) wo += ws[1];
    if (w > 2) wo += ws[2];
    bsum[tid] = wo + p - v;
}

__global__ __launch_bounds__(256) void k_scan3(int* __restrict__ indptr,
        const int* __restrict__ bsum){
    int bid = blockIdx.x;
    int off = bsum[bid];
    int4* p = (int4*)indptr + bid * 256 + threadIdx.x;
    int4 v = *p;
    v.x += off; v.y += off; v.z += off; v.w += off;
    *p = v;
    if (bid == 0 && threadIdx.x == 0) indptr[NNODES] = NEDGE;
}

__global__ void k_fill(const int* __restrict__ src, const int* __restrict__ dst,
        const int* __restrict__ indptr, int* __restrict__ cursor, int* __restrict__ esrc){
    int e = blockIdx.x * blockDim.x + threadIdx.x;
    if (e < NEDGE){
        int d = dst[e];
        int pos = indptr[d] + atomicAdd(&cursor[d], 1);
        esrc[pos] = src[e];
    }
}

// ---------------- W prep: W f32 [KD][128] -> Wt f16 [128][KD] ----------------
__global__ void k_wprep(const float* __restrict__ W, __half* __restrict__ Wt, int KD){
    int idx = blockIdx.x * 256 + threadIdx.x;     // over 128*KD
    int c = idx / KD, k = idx - c * KD;
    Wt[idx] = __float2half(W[k * 128 + c]);
}

// ---------------- MFMA GEMM, KD=128: Y[N,CO] = X[N,128] @ Wt^T (+bias) ----------------
// block: 64 rows, 256 thr (4 waves, 2x2 wave grid of 32rows x CO/2 cols)
template<int CO, bool BIAS>
__global__ __launch_bounds__(256) void k_mfma128(const __half* __restrict__ X,
        const __half* __restrict__ Wt, const float* __restrict__ bias,
        __half* __restrict__ Y){
    constexpr int KD = 128, PD = 136;
    __shared__ __half Xs[64 * PD];
    __shared__ __half Ws[CO * PD];
    const int r0 = blockIdx.x * 64;
    const int tid = threadIdx.x;
    #pragma unroll
    for (int it = 0; it < 4; ++it){
        int idx = tid + it * 256;
        int row = idx >> 4, q = idx & 15;
        uint4 u = ((const uint4*)(X + (size_t)(r0 + row) * KD))[q];
        *(uint4*)(Xs + row * PD + q * 8) = u;
    }
    #pragma unroll
    for (int it = 0; it < CO / 16; ++it){
        int idx = tid + it * 256;
        int row = idx >> 4, q = idx & 15;
        uint4 u = ((const uint4*)(Wt + (size_t)row * KD))[q];
        *(uint4*)(Ws + row * PD + q * 8) = u;
    }
    __syncthreads();
    const int wv = tid >> 6, lane = tid & 63, lr = lane & 15, lh = lane >> 4;
    const int rw = (wv >> 1) * 32;
    const int cw = (wv & 1) * (CO / 2);
    constexpr int CT = CO / 32;
    floatx4 acc[2][CT];
    #pragma unroll
    for (int t = 0; t < 2; ++t)
        #pragma unroll
        for (int ct = 0; ct < CT; ++ct) acc[t][ct] = (floatx4){0.f, 0.f, 0.f, 0.f};
    #pragma unroll
    for (int s = 0; s < 4; ++s){
        int kb = s * 32 + lh * 8;
        half8 a0 = *(const half8*)(Xs + (rw + lr) * PD + kb);
        half8 a1 = *(const half8*)(Xs + (rw + 16 + lr) * PD + kb);
        #pragma unroll
        for (int ct = 0; ct < CT; ++ct){
            half8 b = *(const half8*)(Ws + (cw + ct * 16 + lr) * PD + kb);
            acc[0][ct] = __builtin_amdgcn_mfma_f32_16x16x32_f16(a0, b, acc[0][ct], 0, 0, 0);
            acc[1][ct] = __builtin_amdgcn_mfma_f32_16x16x32_f16(a1, b, acc[1][ct], 0, 0, 0);
        }
    }
    #pragma unroll
    for (int ct = 0; ct < CT; ++ct){
        int col = cw + ct * 16 + lr;
        float bv = BIAS ? bias[col] : 0.f;
        #pragma unroll
        for (int t = 0; t < 2; ++t){
            #pragma unroll
            for (int reg = 0; reg < 4; ++reg){
                int row = r0 + rw + t * 16 + lh * 4 + reg;
                Y[(size_t)row * CO + col] = __float2half(acc[t][ct][reg] + bv);
            }
        }
    }
}

// ---------------- MFMA GEMM layer1: x f32 [N,32] @ Wt1 -> B0 f16 [N,128] ----------------
__global__ __launch_bounds__(256) void k_mfma_l1(const float* __restrict__ X,
        const __half* __restrict__ Wt, __half* __restrict__ Y){
    constexpr int KD = 32, PD = 40, CO = 128;
    __shared__ __half Xs[64 * PD];
    __shared__ __half Ws[CO * PD];
    const int r0 = blockIdx.x * 64;
    const int tid = threadIdx.x;
    #pragma unroll
    for (int it = 0; it < 2; ++it){   // 64 rows * 8 float4 = 512
        int idx = tid + it * 256;
        int row = idx >> 3, q = idx & 7;
        float4 f = ((const float4*)(X + (size_t)(r0 + row) * KD))[q];
        *(__half2*)(Xs + row * PD + q * 4)     = __floats2half2_rn(f.x, f.y);
        *(__half2*)(Xs + row * PD + q * 4 + 2) = __floats2half2_rn(f.z, f.w);
    }
    #pragma unroll
    for (int it = 0; it < 2; ++it){   // 128 rows * 4 u4 = 512
        int idx = tid + it * 256;
        int row = idx >> 2, q = idx & 3;
        uint4 u = ((const uint4*)(Wt + (size_t)row * KD))[q];
        *(uint4*)(Ws + row * PD + q * 8) = u;
    }
    __syncthreads();
    const int wv = tid >> 6, lane = tid & 63, lr = lane & 15, lh = lane >> 4;
    const int rw = (wv >> 1) * 32;
    const int cw = (wv & 1) * 64;
    floatx4 acc[2][4];
    #pragma unroll
    for (int t = 0; t < 2; ++t)
        #pragma unroll
        for (int ct = 0; ct < 4; ++ct) acc[t][ct] = (floatx4){0.f, 0.f, 0.f, 0.f};
    int kb = lh * 8;
    half8 a0 = *(const half8*)(Xs + (rw + lr) * PD + kb);
    half8 a1 = *(const half8*)(Xs + (rw + 16 + lr) * PD + kb);
    #pragma unroll
    for (int ct = 0; ct < 4; ++ct){
        half8 b = *(const half8*)(Ws + (cw + ct * 16 + lr) * PD + kb);
        acc[0][ct] = __builtin_amdgcn_mfma_f32_16x16x32_f16(a0, b, acc[0][ct], 0, 0, 0);
        acc[1][ct] = __builtin_amdgcn_mfma_f32_16x16x32_f16(a1, b, acc[1][ct], 0, 0, 0);
    }
    #pragma unroll
    for (int ct = 0; ct < 4; ++ct){
        int col = cw + ct * 16 + lr;
        #pragma unroll
        for (int t = 0; t < 2; ++t){
            #pragma unroll
            for (int reg = 0; reg < 4; ++reg){
                int row = r0 + rw + t * 16 + lh * 4 + reg;
                Y[(size_t)row * CO + col] = __float2half(acc[t][ct][reg]);
            }
        }
    }
}

// ---------------- copy half: B1[n][0:64] = B0[n][off:off+64] ----------------
__global__ void k_copyh(const __half* __restrict__ B0, __half* __restrict__ B1, int off){
    int i = blockIdx.x * blockDim.x + threadIdx.x;   // N*8 uint4
    if (i >= NNODES * 8) return;
    int node = i >> 3, q = i & 7;
    ((uint4*)B1)[i] = *(const uint4*)((const char*)B0 + (size_t)node * 256 + off * 2 + q * 16);
}

// ---------------- fused gather-aggregate + bias + selu (64-ch half) ----------------
__global__ __launch_bounds__(256) void k_gather64(const int* __restrict__ indptr,
        const int* __restrict__ esrc, const float* __restrict__ dinv,
        const __half* __restrict__ B1, const float* __restrict__ bias,
        __half* __restrict__ B0, int off){
    int t = blockIdx.x * blockDim.x + threadIdx.x;
    int node = t >> 5;
    if (node >= NNODES) return;
    int c2 = t & 31;
    float dn = dinv[node];
    int beg = indptr[node], end = indptr[node + 1];
    float2 sf = __half22float2(((const __half2*)B1)[(size_t)node * 32 + c2]);
    float w0 = dn * dn;
    float ax = sf.x * w0, ay = sf.y * w0;
    for (int j = beg; j < end; ++j){
        int s = esrc[j];
        float norm = dinv[s] * dn;
        float2 f = __half22float2(((const __half2*)B1)[(size_t)s * 32 + c2]);
        ax += f.x * norm;
        ay += f.y * norm;
    }
    ax = selu_f(ax + bias[off + 2 * c2]);
    ay = selu_f(ay + bias[off + 2 * c2 + 1]);
    ((__half2*)B0)[(size_t)node * 64 + off / 2 + c2] = __floats2half2_rn(ax, ay);
}

// ---------------- per-graph masked-node selection + shuffle ----------------
__global__ void k_qnode(const float* __restrict__ x, const int* __restrict__ shuf,
                        int* __restrict__ qnode){
    int b = blockIdx.x;
    int lane = threadIdx.x;   // 64
    __shared__ int list[MAXN];
    int localIdx[16];
    int cnt = 0;
    #pragma unroll
    for (int j = 0; j < 16; ++j){
        int node = lane * 16 + j;
        float m = x[(size_t)(b * NNPG + node) * INCH + (INCH - 3)];
        if (m > 0.5f){ if (cnt < 16) localIdx[cnt] = node; cnt++; }
    }
    int pref = cnt;
    #pragma unroll
    for (int off = 1; off < 64; off <<= 1){
        int v = __shfl_up(pref, off);
        if (lane >= off) pref += v;
    }
    pref -= cnt;
    for (int t = 0; t < cnt; ++t){
        int pos = pref + t;
        if (pos < MAXN) list[pos] = localIdx[t];
    }
    __syncthreads();
    if (lane < MAXN){
        int sidx = shuf[b * MAXN + lane];
        qnode[b * MAXN + lane] = b * NNPG + list[sidx];
    }
}

// ---------------- Q = (h2[qnode] @ Wq + bq) / sqrt(H) ----------------
__global__ __launch_bounds__(128) void k_qgemm(const __half* __restrict__ h, const int* __restrict__ qnode,
        const float* __restrict__ Wq, const float* __restrict__ bq, float* __restrict__ Q){
    __shared__ float hs[HD];
    int row = blockIdx.x;
    int c = threadIdx.x;
    int node = qnode[row];
    if (c < 64){
        float2 f = __half22float2(((const __half2*)h)[(size_t)node * 64 + c]);
        hs[2*c] = f.x; hs[2*c + 1] = f.y;
    }
    __syncthreads();
    float acc = bq[c];
    for (int k = 0; k < HD; ++k) acc += hs[k] * Wq[k * HD + c];
    Q[row * HD + c] = acc * 0.08838834764831845f;
}

// ---------------- scores_t[b][k][i] (+)= Q[b,i,coff:coff+64] . Kh[b*1024+k,:] ----------------
template<bool FIRST>
__global__ __launch_bounds__(256) void k_scores2(const float* __restrict__ Q,
        const __half* __restrict__ Kh, float* __restrict__ st, int coff){
    int b = blockIdx.x, tid = threadIdx.x;
    __shared__ float Qs[MAXN][64];
    #pragma unroll
    for (int it = 0; it < 2; ++it){
        int idx = tid + it * 256;
        Qs[idx >> 6][idx & 63] = Q[(size_t)(b * MAXN + (idx >> 6)) * HD + coff + (idx & 63)];
    }
    __syncthreads();
    int k0 = tid * 4;
    float acc[4][MAXN];
    #pragma unroll
    for (int r = 0; r < 4; ++r)
        #pragma unroll
        for (int i = 0; i < MAXN; ++i) acc[r][i] = 0.f;
    const uint4* rows = (const uint4*)(Kh + ((size_t)b * NNPG + k0) * 64);
    #pragma unroll
    for (int q = 0; q < 8; ++q){
        float f[4][8];
        #pragma unroll
        for (int r = 0; r < 4; ++r){
            uint4 u = rows[r * 8 + q];
            const __half2* hp = (const __half2*)&u;
            #pragma unroll
            for (int j = 0; j < 4; ++j){
                float2 fv = __half22float2(hp[j]);
                f[r][2*j] = fv.x; f[r][2*j+1] = fv.y;
            }
        }
        #pragma unroll
        for (int i = 0; i < MAXN; ++i){
            #pragma unroll
            for (int j = 0; j < 8; ++j){
                float qv = Qs[i][q * 8 + j];
                #pragma unroll
                for (int r = 0; r < 4; ++r) acc[r][i] += f[r][j] * qv;
            }
        }
    }
    #pragma unroll
    for (int r = 0; r < 4; ++r){
        float4* sp = (float4*)(st + ((size_t)b * NNPG + k0 + r) * MAXN);
        if (FIRST){
            sp[0] = make_float4(acc[r][0], acc[r][1], acc[r][2], acc[r][3]);
            sp[1] = make_float4(acc[r][4], acc[r][5], acc[r][6], acc[r][7]);
        } else {
            float4 o0 = sp[0], o1 = sp[1];
            sp[0] = make_float4(o0.x + acc[r][0], o0.y + acc[r][1], o0.z + acc[r][2], o0.w + acc[r][3]);
            sp[1] = make_float4(o1.x + acc[r][4], o1.y + acc[r][5], o1.z + acc[r][6], o1.w + acc[r][7]);
        }
    }
}

// ---------------- softmax over k for each (b,i); scores_t [b][k][8] in-place ----------------
__global__ __launch_bounds__(256) void k_softmax2(float* __restrict__ st){
    int b = blockIdx.x, tid = threadIdx.x;
    int wv = tid >> 6, lane = tid & 63;
    float* base = st + (size_t)b * NNPG * MAXN;
    float v[4][MAXN];
    #pragma unroll
    for (int r = 0; r < 4; ++r){
        int k = tid + r * 256;
        float4 a0 = ((const float4*)(base + k * MAXN))[0];
        float4 a1 = ((const float4*)(base + k * MAXN))[1];
        v[r][0]=a0.x; v[r][1]=a0.y; v[r][2]=a0.z; v[r][3]=a0.w;
        v[r][4]=a1.x; v[r][5]=a1.y; v[r][6]=a1.z; v[r][7]=a1.w;
    }
    float m[MAXN];
    #pragma unroll
    for (int i = 0; i < MAXN; ++i)
        m[i] = fmaxf(fmaxf(v[0][i], v[1][i]), fmaxf(v[2][i], v[3][i]));
    #pragma unroll
    for (int off = 32; off; off >>= 1)
        #pragma unroll
        for (int i = 0; i < MAXN; ++i) m[i] = fmaxf(m[i], __shfl_xor(m[i], off));
    __shared__ float red[2][4][MAXN];
    if (lane == 0)
        #pragma unroll
        for (int i = 0; i < MAXN; ++i) red[0][wv][i] = m[i];
    __syncthreads();
    #pragma unroll
    for (int i = 0; i < MAXN; ++i)
        m[i] = fmaxf(fmaxf(red[0][0][i], red[0][1][i]), fmaxf(red[0][2][i], red[0][3][i]));
    float s[MAXN];
    #pragma unroll
    for (int i = 0; i < MAXN; ++i) s[i] = 0.f;
    #pragma unroll
    for (int r = 0; r < 4; ++r)
        #pragma unroll
        for (int i = 0; i < MAXN; ++i){
            v[r][i] = expf(v[r][i] - m[i]);
            s[i] += v[r][i];
        }
    #pragma unroll
    for (int off = 32; off; off >>= 1)
        #pragma unroll
        for (int i = 0; i < MAXN; ++i) s[i] += __shfl_xor(s[i], off);
    if (lane == 0)
        #pragma unroll
        for (int i = 0; i < MAXN; ++i) red[1][wv][i] = s[i];
    __syncthreads();
    #pragma unroll
    for (int i = 0; i < MAXN; ++i){
        float tot = red[1][0][i] + red[1][1][i] + red[1][2][i] + red[1][3][i];
        s[i] = 1.0f / tot;
    }
    #pragma unroll
    for (int r = 0; r < 4; ++r){
        int k = tid + r * 256;
        float4 a0 = make_float4(v[r][0]*s[0], v[r][1]*s[1], v[r][2]*s[2], v[r][3]*s[3]);
        float4 a1 = make_float4(v[r][4]*s[4], v[r][5]*s[5], v[r][6]*s[6], v[r][7]*s[7]);
        ((float4*)(base + k * MAXN))[0] = a0;
        ((float4*)(base + k * MAXN))[1] = a1;
    }
}

// ---------------- PV half: pvout[b,i,coff:coff+64] = sum_k attn_t[b,k,i] * Vh[b*1024+k,:] ----
__global__ __launch_bounds__(256) void k_pv2(const float* __restrict__ at_g,
        const __half* __restrict__ Vh, float* __restrict__ pvout, int coff){
    int b = blockIdx.x, tid = threadIdx.x;
    __shared__ float at[NNPG * MAXN];     // 32 KB
    __shared__ __half2 Vs[256 * 32];      // 32 KB
    const float4* asrc = (const float4*)(at_g + (size_t)b * NNPG * MAXN);
    #pragma unroll
    for (int it = 0; it < 8; ++it) ((float4*)at)[tid + it * 256] = asrc[tid + it * 256];
    int c2 = tid & 31, ig = tid >> 5;
    float ax = 0.f, ay = 0.f;
    for (int kc = 0; kc < NNPG; kc += 256){
        __syncthreads();
        const uint4* vsrc = (const uint4*)(Vh + ((size_t)b * NNPG + kc) * 64);
        #pragma unroll
        for (int it = 0; it < 8; ++it) ((uint4*)Vs)[tid + it * 256] = vsrc[tid + it * 256];
        __syncthreads();
        for (int k = 0; k < 256; ++k){
            float a = at[(kc + k) * MAXN + ig];
            float2 f = __half22float2(Vs[k * 32 + c2]);
            ax += a * f.x;
            ay += a * f.y;
        }
    }
    float2* op = (float2*)(pvout + (size_t)(b * MAXN + ig) * HD + coff + 2 * c2);
    *op = make_float2(ax, ay);
}

// ---------------- tail: Wo+bo+selu then Wfc+bfc -> out[b][8] ----------------
__global__ __launch_bounds__(256) void k_tail(const float* __restrict__ pvout,
        const float* __restrict__ Wo, const float* __restrict__ bo,
        const float* __restrict__ Wfc, const float* __restrict__ bfc,
        float* __restrict__ out){
    int b = blockIdx.x;
    int tid = threadIdx.x;
    __shared__ float pv[MAXN * HD];
    __shared__ float sol[MAXN * HD];
    __shared__ float red[64];
    for (int idx = tid; idx < MAXN * HD / 4; idx += 256)
        ((float4*)pv)[idx] = ((const float4*)(pvout + (size_t)b * MAXN * HD))[idx];
    __syncthreads();
    int c = tid & 127;
    int grp = tid >> 7;
    float bb = bo[c];
    float acc[4];
    #pragma unroll
    for (int j = 0; j < 4; ++j) acc[j] = bb;
    for (int k = 0; k < HD; ++k){
        float w = Wo[k * HD + c];
        #pragma unroll
        for (int j = 0; j < 4; ++j) acc[j] += pv[(grp*4 + j) * HD + k] * w;
    }
    #pragma unroll
    for (int j = 0; j < 4; ++j) sol[(grp*4 + j) * HD + c] = selu_f(acc[j]);
    __syncthreads();
    if (tid < 64){
        int j = tid & 7;
        int part = tid >> 3;
        float p = 0.f;
        for (int m = part * 128; m < part * 128 + 128; ++m) p += sol[m] * Wfc[m * MAXN + j];
        red[tid] = p;
    }
    __syncthreads();
    if (tid < MAXN){
        float s = bfc[tid];
        #pragma unroll
        for (int part = 0; part < 8; ++part) s += red[part * 8 + tid];
        out[b * MAXN + tid] = s;
    }
}

extern "C" void kernel_launch(void* const* d_in, const int* in_sizes, int n_in,
                              void* d_out, int out_size, void* d_ws, size_t ws_size,
                              hipStream_t stream) {
    const float* x    = (const float*)d_in[0];
    const int*   edge = (const int*)d_in[1];
    const int*   shuf = (const int*)d_in[2];
    const float* W1   = (const float*)d_in[3];
    const float* b1   = (const float*)d_in[4];
    const float* W2   = (const float*)d_in[5];
    const float* b2   = (const float*)d_in[6];
    const float* Wq   = (const float*)d_in[7];
    const float* bq   = (const float*)d_in[8];
    const float* Wk   = (const float*)d_in[9];
    const float* bk   = (const float*)d_in[10];
    const float* Wv   = (const float*)d_in[11];
    const float* bv   = (const float*)d_in[12];
    const float* Wo   = (const float*)d_in[13];
    const float* bo   = (const float*)d_in[14];
    const float* Wfc  = (const float*)d_in[15];
    const float* bfc  = (const float*)d_in[16];
    float* out = (float*)d_out;

    // workspace layout — ~107.1 MiB
    char* w = (char*)d_ws;
    __half* B0    = (__half*)w;  w += (size_t)NNODES * HD * sizeof(__half);    // 64 MiB
    __half* B1    = (__half*)w;  w += (size_t)NNODES * 64 * sizeof(__half);    // 32 MiB
    float*  R1    = (float*)w;   w += (size_t)NNODES * sizeof(float);          // 1 MiB: dinv, later pvout
    int*    R2    = (int*)w;     w += (size_t)NNODES * sizeof(int);            // 1 MiB: deg/cursor, later Qb
    int*    indptr= (int*)w;     w += ((size_t)NNODES + 64) * sizeof(int);
    int*    bsum  = (int*)w;     w += 1024;
    int*    qnode = (int*)w;     w += 8192;
    __half* Wt1   = (__half*)w;  w += 128 * INCH * sizeof(__half);             // 8 KiB
    __half* Wt2   = (__half*)w;  w += 128 * HD * sizeof(__half);               // 32 KiB
    __half* Wtk   = (__half*)w;  w += 128 * HD * sizeof(__half);
    __half* Wtv   = (__half*)w;  w += 128 * HD * sizeof(__half);
    char*   U     = w;           w += (size_t)NGRAPH * MAXN * NNPG * sizeof(float); // 8 MiB
    size_t need = (size_t)(w - (char*)d_ws);
    if (ws_size < need) return;

    float* dinv  = R1;
    float* pvout = R1;            // after gathers
    int*   degcur= R2;
    float* Qb    = (float*)R2;    // after CSR build
    int*   esrc  = (int*)U;       // during GNN layers
    float* st    = (float*)U;     // scores_t during attention

    const int* srcp = edge;
    const int* dstp = edge + NEDGE;

    // ---- CSR build ----
    hipMemsetAsync(degcur, 0, NNODES * sizeof(int), stream);
    k_deg<<<NEDGE / 256, 256, 0, stream>>>(dstp, degcur);
    k_dinv<<<NNODES / 256, 256, 0, stream>>>(degcur, dinv);
    k_scan1<<<256, 256, 0, stream>>>(degcur, indptr, bsum);
    k_scan2<<<1, 256, 0, stream>>>(bsum);
    k_scan3<<<256, 256, 0, stream>>>(indptr, bsum);
    hipMemsetAsync(degcur, 0, NNODES * sizeof(int), stream);
    k_fill<<<NEDGE / 256, 256, 0, stream>>>(srcp, dstp, indptr, degcur, esrc);

    // ---- weight prep ----
    k_wprep<<<(128 * INCH) / 256, 256, 0, stream>>>(W1, Wt1, INCH);
    k_wprep<<<(128 * HD) / 256, 256, 0, stream>>>(W2, Wt2, HD);
    k_wprep<<<(128 * HD) / 256, 256, 0, stream>>>(Wk, Wtk, HD);
    k_wprep<<<(128 * HD) / 256, 256, 0, stream>>>(Wv, Wtv, HD);

    const int cBlocks = (NNODES * 8) / 256;    // copyh
    const int gBlocks = (NNODES * 32) / 256;   // gather

    // ---- layer 1 ----
    k_mfma_l1<<<NNODES / 64, 256, 0, stream>>>(x, Wt1, B0);
    for (int off = 0; off < HD; off += 64){
        k_copyh<<<cBlocks, 256, 0, stream>>>(B0, B1, off);
        k_gather64<<<gBlocks, 256, 0, stream>>>(indptr, esrc, dinv, B1, b1, B0, off);
    }
    // ---- layer 2 (in-place) ----
    k_mfma128<128, false><<<NNODES / 64, 256, 0, stream>>>(B0, Wt2, nullptr, B0);
    for (int off = 0; off < HD; off += 64){
        k_copyh<<<cBlocks, 256, 0, stream>>>(B0, B1, off);
        k_gather64<<<gBlocks, 256, 0, stream>>>(indptr, esrc, dinv, B1, b2, B0, off);
    }
    // ---- attention ----
    k_qnode<<<NGRAPH, 64, 0, stream>>>(x, shuf, qnode);
    k_qgemm<<<NGRAPH * MAXN, 128, 0, stream>>>(B0, qnode, Wq, bq, Qb);

    k_mfma128<64, true><<<NNODES / 64, 256, 0, stream>>>(B0, Wtk, bk, B1);
    k_scores2<true><<<NGRAPH, 256, 0, stream>>>(Qb, B1, st, 0);
    k_mfma128<64, true><<<NNODES / 64, 256, 0, stream>>>(B0, Wtk + 64 * HD, bk + 64, B1);
    k_scores2<false><<<NGRAPH, 256, 0, stream>>>(Qb, B1, st, 64);

    k_softmax2<<<NGRAPH, 256, 0, stream>>>(st);

    k_mfma128<64, true><<<NNODES / 64, 256, 0, stream>>>(B0, Wtv, bv, B1);
    k_pv2<<<NGRAPH, 256, 0, stream>>>(st, B1, pvout, 0);
    k_mfma128<64, true><<<NNODES / 64, 256, 0, stream>>>(B0, Wtv + 64 * HD, bv + 64, B1);
    k_pv2<<<NGRAPH, 256, 0, stream>>>(st, B1, pvout, 64);

    k_tail<<<NGRAPH, 256, 0, stream>>>(pvout, Wo, bo, Wfc, bfc, out);
}

// Round 5
// 893.744 us; speedup vs baseline: 17.5825x; 1.2941x over previous
//
#include <hip/hip_runtime.h>
#include <hip/hip_fp16.h>
#include <math.h>

#define NNODES 262144   // total nodes
#define NNPG   1024     // nodes per graph
#define NGRAPH 256      // graphs
#define INCH   32       // in channels
#define HD     128      // hidden
#define MAXN   8
#define NEDGE  2097152

using half8  = __attribute__((ext_vector_type(8))) _Float16;
using floatx4 = __attribute__((ext_vector_type(4))) float;

__device__ __forceinline__ float selu_f(float v){
    const float alpha = 1.6732632423543772f;
    const float scale = 1.0507009873554805f;
    return v > 0.f ? scale * v : scale * alpha * expm1f(v);
}

// ---------------- degree / dinv ----------------
__global__ void k_deg(const int* __restrict__ dst, int* __restrict__ deg){
    int e = blockIdx.x * blockDim.x + threadIdx.x;
    if (e < NEDGE) atomicAdd(&deg[dst[e]], 1);
}

__global__ void k_dinv(const int* __restrict__ deg, float* __restrict__ dinv){
    int i = blockIdx.x * blockDim.x + threadIdx.x;
    if (i < NNODES) dinv[i] = rsqrtf((float)deg[i] + 1.0f);
}

// ---------------- prefix sum (3-pass) ----------------
__global__ __launch_bounds__(256) void k_scan1(const int* __restrict__ deg,
        int* __restrict__ indptr, int* __restrict__ bsum){
    int bid = blockIdx.x, tid = threadIdx.x;
    int4 v = ((const int4*)deg)[bid * 256 + tid];
    int s = v.x + v.y + v.z + v.w;
    int lane = tid & 63;
    int p = s;
    #pragma unroll
    for (int off = 1; off < 64; off <<= 1){
        int u = __shfl_up(p, off);
        if (lane >= off) p += u;
    }
    __shared__ int ws[4];
    if (lane == 63) ws[tid >> 6] = p;
    __syncthreads();
    int w = tid >> 6, wo = 0;
    if (w > 0) wo = ws[0];
    if (w > 1) wo += ws[1];
    if (w > 2) wo += ws[2];
    int excl = wo + p - s;
    int base = bid * 1024 + tid * 4;
    indptr[base + 0] = excl;
    indptr[base + 1] = excl + v.x;
    indptr[base + 2] = excl + v.x + v.y;
    indptr[base + 3] = excl + v.x + v.y + v.z;
    if (tid == 255) bsum[bid] = excl + s;
}

__global__ __launch_bounds__(256) void k_scan2(int* __restrict__ bsum){
    int tid = threadIdx.x;
    int v = bsum[tid];
    int lane = tid & 63;
    int p = v;
    #pragma unroll
    for (int off = 1; off < 64; off <<= 1){
        int u = __shfl_up(p, off);
        if (lane >= off) p += u;
    }
    __shared__ int ws[4];
    if (lane == 63) ws[tid >> 6] = p;
    __syncthreads();
    int w = tid >> 6, wo = 0;
    if (w > 0) wo = ws[0];
    if (w > 1) wo += ws[1];
    if (w > 2) wo += ws[2];
    bsum[tid] = wo + p - v;
}

__global__ __launch_bounds__(256) void k_scan3(int* __restrict__ indptr,
        const int* __restrict__ bsum){
    int bid = blockIdx.x;
    int off = bsum[bid];
    int4* p = (int4*)indptr + bid * 256 + threadIdx.x;
    int4 v = *p;
    v.x += off; v.y += off; v.z += off; v.w += off;
    *p = v;
    if (bid == 0 && threadIdx.x == 0) indptr[NNODES] = NEDGE;
}

__global__ void k_fill(const int* __restrict__ src, const int* __restrict__ dst,
        const int* __restrict__ indptr, int* __restrict__ cursor, int* __restrict__ esrc){
    int e = blockIdx.x * blockDim.x + threadIdx.x;
    if (e < NEDGE){
        int d = dst[e];
        int pos = indptr[d] + atomicAdd(&cursor[d], 1);
        esrc[pos] = src[e];
    }
}

// ---------------- W prep: W f32 [KD][128] -> Wt f16 [128][KD] ----------------
__global__ void k_wprep(const float* __restrict__ W, __half* __restrict__ Wt, int KD){
    int idx = blockIdx.x * 256 + threadIdx.x;     // over 128*KD
    int c = idx / KD, k = idx - c * KD;
    Wt[idx] = __float2half(W[k * 128 + c]);
}

// ---------------- MFMA GEMM with split-A [N,128]: cols 0-63 from Alo, 64-127 from Ahi ----
// Y[r][c] = (A[r] . Wt[c]) (+bias[c]) (*dinv[r] if SCALE); Y row stride sY halfs.
template<int CO, bool BIAS, bool SCALE>
__global__ __launch_bounds__(256) void k_mfma_sp(const __half* __restrict__ Alo, int sLo,
        const __half* __restrict__ Ahi, int sHi,
        const __half* __restrict__ Wt, const float* __restrict__ bias,
        const float* __restrict__ dinv,
        __half* __restrict__ Y, int sY){
    constexpr int KD = 128, PD = 136;
    __shared__ __half Xsm[64 * PD];
    __shared__ __half Wsm[CO * PD];
    __shared__ float dvs[64];
    const int r0 = blockIdx.x * 64;
    const int tid = threadIdx.x;
    #pragma unroll
    for (int it = 0; it < 2; ++it){
        int idx = tid + it * 256;       // 512 = 64 rows x 8 uint4
        int row = idx >> 3, q = idx & 7;
        uint4 u = *(const uint4*)(Alo + (size_t)(r0 + row) * sLo + q * 8);
        *(uint4*)(Xsm + row * PD + q * 8) = u;
        uint4 v = *(const uint4*)(Ahi + (size_t)(r0 + row) * sHi + q * 8);
        *(uint4*)(Xsm + row * PD + 64 + q * 8) = v;
    }
    #pragma unroll
    for (int it = 0; it < CO / 16; ++it){
        int idx = tid + it * 256;
        int row = idx >> 4, q = idx & 15;
        uint4 u = ((const uint4*)(Wt + (size_t)row * KD))[q];
        *(uint4*)(Wsm + row * PD + q * 8) = u;
    }
    if (SCALE && tid < 64) dvs[tid] = dinv[r0 + tid];
    __syncthreads();
    const int wv = tid >> 6, lane = tid & 63, lr = lane & 15, lh = lane >> 4;
    const int rw = (wv >> 1) * 32;
    const int cw = (wv & 1) * (CO / 2);
    constexpr int CT = CO / 32;
    floatx4 acc[2][CT];
    #pragma unroll
    for (int t = 0; t < 2; ++t)
        #pragma unroll
        for (int ct = 0; ct < CT; ++ct) acc[t][ct] = (floatx4){0.f, 0.f, 0.f, 0.f};
    #pragma unroll
    for (int s = 0; s < 4; ++s){
        int kb = s * 32 + lh * 8;
        half8 a0 = *(const half8*)(Xsm + (rw + lr) * PD + kb);
        half8 a1 = *(const half8*)(Xsm + (rw + 16 + lr) * PD + kb);
        #pragma unroll
        for (int ct = 0; ct < CT; ++ct){
            half8 b = *(const half8*)(Wsm + (cw + ct * 16 + lr) * PD + kb);
            acc[0][ct] = __builtin_amdgcn_mfma_f32_16x16x32_f16(a0, b, acc[0][ct], 0, 0, 0);
            acc[1][ct] = __builtin_amdgcn_mfma_f32_16x16x32_f16(a1, b, acc[1][ct], 0, 0, 0);
        }
    }
    #pragma unroll
    for (int ct = 0; ct < CT; ++ct){
        int col = cw + ct * 16 + lr;
        float bv = BIAS ? bias[col] : 0.f;
        #pragma unroll
        for (int t = 0; t < 2; ++t){
            #pragma unroll
            for (int reg = 0; reg < 4; ++reg){
                int rl = rw + t * 16 + lh * 4 + reg;
                float v = acc[t][ct][reg];
                if (SCALE) v *= dvs[rl];
                Y[(size_t)(r0 + rl) * sY + col] = __float2half(v + bv);
            }
        }
    }
}

// ---------------- MFMA layer1: x f32 [N,32] @ Wt1, scaled by dinv -> B0 f16 [N,128] ----
__global__ __launch_bounds__(256) void k_mfma_l1(const float* __restrict__ X,
        const __half* __restrict__ Wt, const float* __restrict__ dinv,
        __half* __restrict__ Y){
    constexpr int KD = 32, PD = 40, CO = 128;
    __shared__ __half Xs[64 * PD];
    __shared__ __half Ws[CO * PD];
    __shared__ float dvs[64];
    const int r0 = blockIdx.x * 64;
    const int tid = threadIdx.x;
    #pragma unroll
    for (int it = 0; it < 2; ++it){   // 64 rows * 8 float4 = 512
        int idx = tid + it * 256;
        int row = idx >> 3, q = idx & 7;
        float4 f = ((const float4*)(X + (size_t)(r0 + row) * KD))[q];
        *(__half2*)(Xs + row * PD + q * 4)     = __floats2half2_rn(f.x, f.y);
        *(__half2*)(Xs + row * PD + q * 4 + 2) = __floats2half2_rn(f.z, f.w);
    }
    #pragma unroll
    for (int it = 0; it < 2; ++it){   // 128 rows * 4 u4 = 512
        int idx = tid + it * 256;
        int row = idx >> 2, q = idx & 3;
        uint4 u = ((const uint4*)(Wt + (size_t)row * KD))[q];
        *(uint4*)(Ws + row * PD + q * 8) = u;
    }
    if (tid < 64) dvs[tid] = dinv[r0 + tid];
    __syncthreads();
    const int wv = tid >> 6, lane = tid & 63, lr = lane & 15, lh = lane >> 4;
    const int rw = (wv >> 1) * 32;
    const int cw = (wv & 1) * 64;
    floatx4 acc[2][4];
    #pragma unroll
    for (int t = 0; t < 2; ++t)
        #pragma unroll
        for (int ct = 0; ct < 4; ++ct) acc[t][ct] = (floatx4){0.f, 0.f, 0.f, 0.f};
    int kb = lh * 8;
    half8 a0 = *(const half8*)(Xs + (rw + lr) * PD + kb);
    half8 a1 = *(const half8*)(Xs + (rw + 16 + lr) * PD + kb);
    #pragma unroll
    for (int ct = 0; ct < 4; ++ct){
        half8 b = *(const half8*)(Ws + (cw + ct * 16 + lr) * PD + kb);
        acc[0][ct] = __builtin_amdgcn_mfma_f32_16x16x32_f16(a0, b, acc[0][ct], 0, 0, 0);
        acc[1][ct] = __builtin_amdgcn_mfma_f32_16x16x32_f16(a1, b, acc[1][ct], 0, 0, 0);
    }
    #pragma unroll
    for (int ct = 0; ct < 4; ++ct){
        int col = cw + ct * 16 + lr;
        #pragma unroll
        for (int t = 0; t < 2; ++t){
            #pragma unroll
            for (int reg = 0; reg < 4; ++reg){
                int rl = rw + t * 16 + lh * 4 + reg;
                Y[(size_t)(r0 + rl) * CO + col] = __float2half(acc[t][ct][reg] * dvs[rl]);
            }
        }
    }
}

// ---------------- fused gather + bias + selu, 64-ch, ILP-4, pre-scaled rows ----------------
// h[node] = selu( dinv[node] * (self + sum_nbr scaled_xw[s]) + bias )
__global__ __launch_bounds__(256) void k_gather64(const int* __restrict__ indptr,
        const int* __restrict__ esrc, const float* __restrict__ dinv,
        const __half2* __restrict__ Xs, int xs2,
        const float* __restrict__ bias, int boff,
        __half2* __restrict__ Yo, int ys2){
    int t = blockIdx.x * blockDim.x + threadIdx.x;
    int node = t >> 5;
    if (node >= NNODES) return;
    int c2 = t & 31;
    float dn = dinv[node];
    int beg = indptr[node], end = indptr[node + 1];
    float2 a = __half22float2(Xs[(size_t)node * xs2 + c2]);
    float ax = a.x, ay = a.y;
    int j = beg;
    for (; j + 4 <= end; j += 4){
        int s0 = esrc[j], s1 = esrc[j+1], s2 = esrc[j+2], s3 = esrc[j+3];
        __half2 f0 = Xs[(size_t)s0 * xs2 + c2];
        __half2 f1 = Xs[(size_t)s1 * xs2 + c2];
        __half2 f2 = Xs[(size_t)s2 * xs2 + c2];
        __half2 f3 = Xs[(size_t)s3 * xs2 + c2];
        float2 g0 = __half22float2(f0), g1 = __half22float2(f1);
        float2 g2 = __half22float2(f2), g3 = __half22float2(f3);
        ax += (g0.x + g1.x) + (g2.x + g3.x);
        ay += (g0.y + g1.y) + (g2.y + g3.y);
    }
    for (; j < end; ++j){
        float2 g = __half22float2(Xs[(size_t)esrc[j] * xs2 + c2]);
        ax += g.x; ay += g.y;
    }
    ax = selu_f(ax * dn + bias[boff + 2 * c2]);
    ay = selu_f(ay * dn + bias[boff + 2 * c2 + 1]);
    Yo[(size_t)node * ys2 + c2] = __floats2half2_rn(ax, ay);
}

// ---------------- per-graph masked-node selection + shuffle ----------------
__global__ void k_qnode(const float* __restrict__ x, const int* __restrict__ shuf,
                        int* __restrict__ qnode){
    int b = blockIdx.x;
    int lane = threadIdx.x;   // 64
    __shared__ int list[MAXN];
    int localIdx[16];
    int cnt = 0;
    #pragma unroll
    for (int j = 0; j < 16; ++j){
        int node = lane * 16 + j;
        float m = x[(size_t)(b * NNPG + node) * INCH + (INCH - 3)];
        if (m > 0.5f){ if (cnt < 16) localIdx[cnt] = node; cnt++; }
    }
    int pref = cnt;
    #pragma unroll
    for (int off = 1; off < 64; off <<= 1){
        int v = __shfl_up(pref, off);
        if (lane >= off) pref += v;
    }
    pref -= cnt;
    for (int t = 0; t < cnt; ++t){
        int pos = pref + t;
        if (pos < MAXN) list[pos] = localIdx[t];
    }
    __syncthreads();
    if (lane < MAXN){
        int sidx = shuf[b * MAXN + lane];
        qnode[b * MAXN + lane] = b * NNPG + list[sidx];
    }
}

// ---------------- Q = (h2[qnode] @ Wq + bq) / sqrt(H); h2 split in B1/B0 ----------------
__global__ __launch_bounds__(128) void k_qgemm(const __half* __restrict__ hLo,
        const __half* __restrict__ hHi, const int* __restrict__ qnode,
        const float* __restrict__ Wq, const float* __restrict__ bq, float* __restrict__ Q){
    __shared__ float hs[HD];
    int row = blockIdx.x;
    int c = threadIdx.x;
    int node = qnode[row];
    if (c < 64) hs[c] = __half2float(hLo[(size_t)node * 64 + c]);
    else        hs[c] = __half2float(hHi[(size_t)node * 128 + (c - 64)]);
    __syncthreads();
    float acc = bq[c];
    for (int k = 0; k < HD; ++k) acc += hs[k] * Wq[k * HD + c];
    Q[row * HD + c] = acc * 0.08838834764831845f;
}

// ---------------- scores_t[b][k][i] (+)= Q[b,i,coff:coff+64] . Kh[b*1024+k,:] ----------------
template<bool FIRST>
__global__ __launch_bounds__(256) void k_scores2(const float* __restrict__ Q,
        const __half* __restrict__ Kh, int sK, float* __restrict__ st, int coff){
    int b = blockIdx.x, tid = threadIdx.x;
    __shared__ float Qs[MAXN][64];
    #pragma unroll
    for (int it = 0; it < 2; ++it){
        int idx = tid + it * 256;
        Qs[idx >> 6][idx & 63] = Q[(size_t)(b * MAXN + (idx >> 6)) * HD + coff + (idx & 63)];
    }
    __syncthreads();
    int k0 = tid * 4;
    const int s4 = sK >> 3;
    float acc[4][MAXN];
    #pragma unroll
    for (int r = 0; r < 4; ++r)
        #pragma unroll
        for (int i = 0; i < MAXN; ++i) acc[r][i] = 0.f;
    const uint4* rows = (const uint4*)(Kh + ((size_t)b * NNPG + k0) * sK);
    #pragma unroll
    for (int q = 0; q < 8; ++q){
        float f[4][8];
        #pragma unroll
        for (int r = 0; r < 4; ++r){
            uint4 u = rows[r * s4 + q];
            const __half2* hp = (const __half2*)&u;
            #pragma unroll
            for (int j = 0; j < 4; ++j){
                float2 fv = __half22float2(hp[j]);
                f[r][2*j] = fv.x; f[r][2*j+1] = fv.y;
            }
        }
        #pragma unroll
        for (int i = 0; i < MAXN; ++i){
            #pragma unroll
            for (int j = 0; j < 8; ++j){
                float qv = Qs[i][q * 8 + j];
                #pragma unroll
                for (int r = 0; r < 4; ++r) acc[r][i] += f[r][j] * qv;
            }
        }
    }
    #pragma unroll
    for (int r = 0; r < 4; ++r){
        float4* sp = (float4*)(st + ((size_t)b * NNPG + k0 + r) * MAXN);
        if (FIRST){
            sp[0] = make_float4(acc[r][0], acc[r][1], acc[r][2], acc[r][3]);
            sp[1] = make_float4(acc[r][4], acc[r][5], acc[r][6], acc[r][7]);
        } else {
            float4 o0 = sp[0], o1 = sp[1];
            sp[0] = make_float4(o0.x + acc[r][0], o0.y + acc[r][1], o0.z + acc[r][2], o0.w + acc[r][3]);
            sp[1] = make_float4(o1.x + acc[r][4], o1.y + acc[r][5], o1.z + acc[r][6], o1.w + acc[r][7]);
        }
    }
}

// ---------------- softmax over k for each (b,i); scores_t [b][k][8] in-place ----------------
__global__ __launch_bounds__(256) void k_softmax2(float* __restrict__ st){
    int b = blockIdx.x, tid = threadIdx.x;
    int wv = tid >> 6, lane = tid & 63;
    float* base = st + (size_t)b * NNPG * MAXN;
    float v[4][MAXN];
    #pragma unroll
    for (int r = 0; r < 4; ++r){
        int k = tid + r * 256;
        float4 a0 = ((const float4*)(base + k * MAXN))[0];
        float4 a1 = ((const float4*)(base + k * MAXN))[1];
        v[r][0]=a0.x; v[r][1]=a0.y; v[r][2]=a0.z; v[r][3]=a0.w;
        v[r][4]=a1.x; v[r][5]=a1.y; v[r][6]=a1.z; v[r][7]=a1.w;
    }
    float m[MAXN];
    #pragma unroll
    for (int i = 0; i < MAXN; ++i)
        m[i] = fmaxf(fmaxf(v[0][i], v[1][i]), fmaxf(v[2][i], v[3][i]));
    #pragma unroll
    for (int off = 32; off; off >>= 1)
        #pragma unroll
        for (int i = 0; i < MAXN; ++i) m[i] = fmaxf(m[i], __shfl_xor(m[i], off));
    __shared__ float red[2][4][MAXN];
    if (lane == 0)
        #pragma unroll
        for (int i = 0; i < MAXN; ++i) red[0][wv][i] = m[i];
    __syncthreads();
    #pragma unroll
    for (int i = 0; i < MAXN; ++i)
        m[i] = fmaxf(fmaxf(red[0][0][i], red[0][1][i]), fmaxf(red[0][2][i], red[0][3][i]));
    float s[MAXN];
    #pragma unroll
    for (int i = 0; i < MAXN; ++i) s[i] = 0.f;
    #pragma unroll
    for (int r = 0; r < 4; ++r)
        #pragma unroll
        for (int i = 0; i < MAXN; ++i){
            v[r][i] = expf(v[r][i] - m[i]);
            s[i] += v[r][i];
        }
    #pragma unroll
    for (int off = 32; off; off >>= 1)
        #pragma unroll
        for (int i = 0; i < MAXN; ++i) s[i] += __shfl_xor(s[i], off);
    if (lane == 0)
        #pragma unroll
        for (int i = 0; i < MAXN; ++i) red[1][wv][i] = s[i];
    __syncthreads();
    #pragma unroll
    for (int i = 0; i < MAXN; ++i){
        float tot = red[1][0][i] + red[1][1][i] + red[1][2][i] + red[1][3][i];
        s[i] = 1.0f / tot;
    }
    #pragma unroll
    for (int r = 0; r < 4; ++r){
        int k = tid + r * 256;
        float4 a0 = make_float4(v[r][0]*s[0], v[r][1]*s[1], v[r][2]*s[2], v[r][3]*s[3]);
        float4 a1 = make_float4(v[r][4]*s[4], v[r][5]*s[5], v[r][6]*s[6], v[r][7]*s[7]);
        ((float4*)(base + k * MAXN))[0] = a0;
        ((float4*)(base + k * MAXN))[1] = a1;
    }
}

// ---------------- PV half: pvout[b,i,coff:coff+64] = sum_k attn_t[b,k,i] * Vh[b*1024+k,:] ----
__global__ __launch_bounds__(256) void k_pv2(const float* __restrict__ at_g,
        const __half* __restrict__ Vh, int sV, float* __restrict__ pvout, int coff){
    int b = blockIdx.x, tid = threadIdx.x;
    __shared__ float at[NNPG * MAXN];     // 32 KB
    __shared__ __half2 Vs[256 * 32];      // 32 KB
    const float4* asrc = (const float4*)(at_g + (size_t)b * NNPG * MAXN);
    #pragma unroll
    for (int it = 0; it < 8; ++it) ((float4*)at)[tid + it * 256] = asrc[tid + it * 256];
    int c2 = tid & 31, ig = tid >> 5;
    const int s4 = sV >> 3;
    float ax = 0.f, ay = 0.f;
    for (int kc = 0; kc < NNPG; kc += 256){
        __syncthreads();
        const uint4* vsrc = (const uint4*)(Vh + (size_t)(b * NNPG + kc) * sV);
        #pragma unroll
        for (int it = 0; it < 8; ++it){
            int idx = tid + it * 256;
            int row = idx >> 3, q = idx & 7;
            ((uint4*)Vs)[idx] = vsrc[row * s4 + q];
        }
        __syncthreads();
        for (int k = 0; k < 256; ++k){
            float a = at[(kc + k) * MAXN + ig];
            float2 f = __half22float2(Vs[k * 32 + c2]);
            ax += a * f.x;
            ay += a * f.y;
        }
    }
    float2* op = (float2*)(pvout + (size_t)(b * MAXN + ig) * HD + coff + 2 * c2);
    *op = make_float2(ax, ay);
}

// ---------------- tail: Wo+bo+selu then Wfc+bfc -> out[b][8] ----------------
__global__ __launch_bounds__(256) void k_tail(const float* __restrict__ pvout,
        const float* __restrict__ Wo, const float* __restrict__ bo,
        const float* __restrict__ Wfc, const float* __restrict__ bfc,
        float* __restrict__ out){
    int b = blockIdx.x;
    int tid = threadIdx.x;
    __shared__ float pv[MAXN * HD];
    __shared__ float sol[MAXN * HD];
    __shared__ float red[64];
    for (int idx = tid; idx < MAXN * HD / 4; idx += 256)
        ((float4*)pv)[idx] = ((const float4*)(pvout + (size_t)b * MAXN * HD))[idx];
    __syncthreads();
    int c = tid & 127;
    int grp = tid >> 7;
    float bb = bo[c];
    float acc[4];
    #pragma unroll
    for (int j = 0; j < 4; ++j) acc[j] = bb;
    for (int k = 0; k < HD; ++k){
        float w = Wo[k * HD + c];
        #pragma unroll
        for (int j = 0; j < 4; ++j) acc[j] += pv[(grp*4 + j) * HD + k] * w;
    }
    #pragma unroll
    for (int j = 0; j < 4; ++j) sol[(grp*4 + j) * HD + c] = selu_f(acc[j]);
    __syncthreads();
    if (tid < 64){
        int j = tid & 7;
        int part = tid >> 3;
        float p = 0.f;
        for (int m = part * 128; m < part * 128 + 128; ++m) p += sol[m] * Wfc[m * MAXN + j];
        red[tid] = p;
    }
    __syncthreads();
    if (tid < MAXN){
        float s = bfc[tid];
        #pragma unroll
        for (int part = 0; part < 8; ++part) s += red[part * 8 + tid];
        out[b * MAXN + tid] = s;
    }
}

extern "C" void kernel_launch(void* const* d_in, const int* in_sizes, int n_in,
                              void* d_out, int out_size, void* d_ws, size_t ws_size,
                              hipStream_t stream) {
    const float* x    = (const float*)d_in[0];
    const int*   edge = (const int*)d_in[1];
    const int*   shuf = (const int*)d_in[2];
    const float* W1   = (const float*)d_in[3];
    const float* b1   = (const float*)d_in[4];
    const float* W2   = (const float*)d_in[5];
    const float* b2   = (const float*)d_in[6];
    const float* Wq   = (const float*)d_in[7];
    const float* bq   = (const float*)d_in[8];
    const float* Wk   = (const float*)d_in[9];
    const float* bk   = (const float*)d_in[10];
    const float* Wv   = (const float*)d_in[11];
    const float* bv   = (const float*)d_in[12];
    const float* Wo   = (const float*)d_in[13];
    const float* bo   = (const float*)d_in[14];
    const float* Wfc  = (const float*)d_in[15];
    const float* bfc  = (const float*)d_in[16];
    float* out = (float*)d_out;

    // workspace layout — ~107.1 MiB
    char* w = (char*)d_ws;
    __half* B0    = (__half*)w;  w += (size_t)NNODES * HD * sizeof(__half);    // 64 MiB
    __half* B1    = (__half*)w;  w += (size_t)NNODES * 64 * sizeof(__half);    // 32 MiB
    float*  R1    = (float*)w;   w += (size_t)NNODES * sizeof(float);          // 1 MiB: dinv (pvout after)
    int*    R2    = (int*)w;     w += (size_t)NNODES * sizeof(int);            // 1 MiB: deg/cursor (Qb after)
    int*    indptr= (int*)w;     w += ((size_t)NNODES + 64) * sizeof(int);
    int*    bsum  = (int*)w;     w += 1024;
    int*    qnode = (int*)w;     w += 8192;
    __half* Wt1   = (__half*)w;  w += 128 * INCH * sizeof(__half);
    __half* Wt2   = (__half*)w;  w += 128 * HD * sizeof(__half);
    __half* Wtk   = (__half*)w;  w += 128 * HD * sizeof(__half);
    __half* Wtv   = (__half*)w;  w += 128 * HD * sizeof(__half);
    char*   U     = w;           w += (size_t)NGRAPH * MAXN * NNPG * sizeof(float); // 8 MiB
    size_t need = (size_t)(w - (char*)d_ws);
    if (ws_size < need) return;

    float* dinv  = R1;
    float* pvout = R1;            // reused after layer-2 gathers
    int*   degcur= R2;
    float* Qb    = (float*)R2;    // reused after CSR build
    int*   esrc  = (int*)U;       // GNN phase
    float* st    = (float*)U;     // attention phase

    const int* srcp = edge;
    const int* dstp = edge + NEDGE;

    // ---- CSR build ----
    hipMemsetAsync(degcur, 0, NNODES * sizeof(int), stream);
    k_deg<<<NEDGE / 256, 256, 0, stream>>>(dstp, degcur);
    k_dinv<<<NNODES / 256, 256, 0, stream>>>(degcur, dinv);
    k_scan1<<<256, 256, 0, stream>>>(degcur, indptr, bsum);
    k_scan2<<<1, 256, 0, stream>>>(bsum);
    k_scan3<<<256, 256, 0, stream>>>(indptr, bsum);
    hipMemsetAsync(degcur, 0, NNODES * sizeof(int), stream);
    k_fill<<<NEDGE / 256, 256, 0, stream>>>(srcp, dstp, indptr, degcur, esrc);

    // ---- weight prep ----
    k_wprep<<<(128 * INCH) / 256, 256, 0, stream>>>(W1, Wt1, INCH);
    k_wprep<<<(128 * HD) / 256, 256, 0, stream>>>(W2, Wt2, HD);
    k_wprep<<<(128 * HD) / 256, 256, 0, stream>>>(Wk, Wtk, HD);
    k_wprep<<<(128 * HD) / 256, 256, 0, stream>>>(Wv, Wtv, HD);

    const int gBlocks = (NNODES * 32) / 256;   // gather grid

    // ---- layer 1: scaled xw1 full in B0; gather h0->B1, h1->B0[:,0:64] ----
    k_mfma_l1<<<NNODES / 64, 256, 0, stream>>>(x, Wt1, dinv, B0);
    k_gather64<<<gBlocks, 256, 0, stream>>>(indptr, esrc, dinv,
            (const __half2*)B0, 64, b1, 0, (__half2*)B1, 32);
    k_gather64<<<gBlocks, 256, 0, stream>>>(indptr, esrc, dinv,
            (const __half2*)(B0 + 64), 64, b1, 64, (__half2*)B0, 64);
    // ---- layer 2: split-A GEMM -> scaled xw2 full in B0 (in-place); gathers ----
    k_mfma_sp<128, false, true><<<NNODES / 64, 256, 0, stream>>>(
            B1, 64, B0, 128, Wt2, nullptr, dinv, B0, 128);
    k_gather64<<<gBlocks, 256, 0, stream>>>(indptr, esrc, dinv,
            (const __half2*)B0, 64, b2, 0, (__half2*)B1, 32);
    k_gather64<<<gBlocks, 256, 0, stream>>>(indptr, esrc, dinv,
            (const __half2*)(B0 + 64), 64, b2, 64, (__half2*)B0, 64);
    // h2: cols 0-63 in B1 (stride 64), cols 64-127 in B0[:,0:64] (stride 128)

    // ---- attention ----
    k_qnode<<<NGRAPH, 64, 0, stream>>>(x, shuf, qnode);
    k_qgemm<<<NGRAPH * MAXN, 128, 0, stream>>>(B1, B0, qnode, Wq, bq, Qb);

    __half* KV = B0 + 64;   // [N,64] at stride 128 — dead region of B0
    k_mfma_sp<64, true, false><<<NNODES / 64, 256, 0, stream>>>(
            B1, 64, B0, 128, Wtk, bk, nullptr, KV, 128);
    k_scores2<true><<<NGRAPH, 256, 0, stream>>>(Qb, KV, 128, st, 0);
    k_mfma_sp<64, true, false><<<NNODES / 64, 256, 0, stream>>>(
            B1, 64, B0, 128, Wtk + 64 * HD, bk + 64, nullptr, KV, 128);
    k_scores2<false><<<NGRAPH, 256, 0, stream>>>(Qb, KV, 128, st, 64);

    k_softmax2<<<NGRAPH, 256, 0, stream>>>(st);

    k_mfma_sp<64, true, false><<<NNODES / 64, 256, 0, stream>>>(
            B1, 64, B0, 128, Wtv, bv, nullptr, KV, 128);
    k_pv2<<<NGRAPH, 256, 0, stream>>>(st, KV, 128, pvout, 0);
    k_mfma_sp<64, true, false><<<NNODES / 64, 256, 0, stream>>>(
            B1, 64, B0, 128, Wtv + 64 * HD, bv + 64, nullptr, KV, 128);
    k_pv2<<<NGRAPH, 256, 0, stream>>>(st, KV, 128, pvout, 64);

    k_tail<<<NGRAPH, 256, 0, stream>>>(pvout, Wo, bo, Wfc, bfc, out);
}

// Round 7
// 850.372 us; speedup vs baseline: 18.4793x; 1.0510x over previous
//
#include <hip/hip_runtime.h>
#include <hip/hip_fp16.h>
#include <math.h>

#define NNODES 262144   // total nodes
#define NNPG   1024     // nodes per graph
#define NGRAPH 256      // graphs
#define INCH   32       // in channels
#define HD     128      // hidden
#define MAXN   8
#define NEDGE  2097152

using half8  = __attribute__((ext_vector_type(8))) _Float16;
using floatx4 = __attribute__((ext_vector_type(4))) float;

__device__ __forceinline__ float selu_f(float v){
    const float alpha = 1.6732632423543772f;
    const float scale = 1.0507009873554805f;
    return v > 0.f ? scale * v : scale * alpha * expm1f(v);
}

// ---------------- degree (ILP-4) ----------------
__global__ void k_deg(const int* __restrict__ dst, int* __restrict__ deg){
    int e4 = blockIdx.x * blockDim.x + threadIdx.x;   // NEDGE/4 threads
    int4 d = ((const int4*)dst)[e4];
    atomicAdd(&deg[d.x], 1);
    atomicAdd(&deg[d.y], 1);
    atomicAdd(&deg[d.z], 1);
    atomicAdd(&deg[d.w], 1);
}

__global__ void k_dinv(const int* __restrict__ deg, float* __restrict__ dinv){
    int i = blockIdx.x * blockDim.x + threadIdx.x;
    if (i < NNODES) dinv[i] = rsqrtf((float)deg[i] + 1.0f);
}

// ---------------- prefix sum (3-pass) ----------------
__global__ __launch_bounds__(256) void k_scan1(const int* __restrict__ deg,
        int* __restrict__ indptr, int* __restrict__ bsum){
    int bid = blockIdx.x, tid = threadIdx.x;
    int4 v = ((const int4*)deg)[bid * 256 + tid];
    int s = v.x + v.y + v.z + v.w;
    int lane = tid & 63;
    int p = s;
    #pragma unroll
    for (int off = 1; off < 64; off <<= 1){
        int u = __shfl_up(p, off);
        if (lane >= off) p += u;
    }
    __shared__ int ws[4];
    if (lane == 63) ws[tid >> 6] = p;
    __syncthreads();
    int w = tid >> 6, wo = 0;
    if (w > 0) wo = ws[0];
    if (w > 1) wo += ws[1];
    if (w > 2) wo += ws[2];
    int excl = wo + p - s;
    int base = bid * 1024 + tid * 4;
    indptr[base + 0] = excl;
    indptr[base + 1] = excl + v.x;
    indptr[base + 2] = excl + v.x + v.y;
    indptr[base + 3] = excl + v.x + v.y + v.z;
    if (tid == 255) bsum[bid] = excl + s;
}

__global__ __launch_bounds__(256) void k_scan2(int* __restrict__ bsum){
    int tid = threadIdx.x;
    int v = bsum[tid];
    int lane = tid & 63;
    int p = v;
    #pragma unroll
    for (int off = 1; off < 64; off <<= 1){
        int u = __shfl_up(p, off);
        if (lane >= off) p += u;
    }
    __shared__ int ws[4];
    if (lane == 63) ws[tid >> 6] = p;
    __syncthreads();
    int w = tid >> 6, wo = 0;
    if (w > 0) wo = ws[0];
    if (w > 1) wo += ws[1];
    if (w > 2) wo += ws[2];
    bsum[tid] = wo + p - v;
}

__global__ __launch_bounds__(256) void k_scan3(int* __restrict__ indptr,
        const int* __restrict__ bsum){
    int bid = blockIdx.x;
    int off = bsum[bid];
    int4* p = (int4*)indptr + bid * 256 + threadIdx.x;
    int4 v = *p;
    v.x += off; v.y += off; v.z += off; v.w += off;
    *p = v;
    if (bid == 0 && threadIdx.x == 0) indptr[NNODES] = NEDGE;
}

// ---------------- fill CSR (ILP-4) ----------------
__global__ void k_fill(const int* __restrict__ src, const int* __restrict__ dst,
        const int* __restrict__ indptr, int* __restrict__ cursor, int* __restrict__ esrc){
    int e4 = blockIdx.x * blockDim.x + threadIdx.x;
    int4 s = ((const int4*)src)[e4];
    int4 d = ((const int4*)dst)[e4];
    int p0 = indptr[d.x] + atomicAdd(&cursor[d.x], 1);
    int p1 = indptr[d.y] + atomicAdd(&cursor[d.y], 1);
    int p2 = indptr[d.z] + atomicAdd(&cursor[d.z], 1);
    int p3 = indptr[d.w] + atomicAdd(&cursor[d.w], 1);
    esrc[p0] = s.x;
    esrc[p1] = s.y;
    esrc[p2] = s.z;
    esrc[p3] = s.w;
}

// ---------------- W prep: W f32 [KD][128] -> Wt f16 [128][KD] ----------------
__global__ void k_wprep(const float* __restrict__ W, __half* __restrict__ Wt, int KD){
    int idx = blockIdx.x * 256 + threadIdx.x;
    int c = idx / KD, k = idx - c * KD;
    Wt[idx] = __float2half(W[k * 128 + c]);
}

// ---------------- shared MFMA core: split-A [64 rows,128] @ Wt[128][128] -> acc ----
__device__ __forceinline__ void mfma128_stage(const __half* __restrict__ Alo,
        const __half* __restrict__ Ahi, const __half* __restrict__ Wt,
        __half* Xsm, __half* Wsm, int r0, int tid){
    #pragma unroll
    for (int it = 0; it < 2; ++it){
        int idx = tid + it * 256;       // 512 = 64 rows x 8 uint4
        int row = idx >> 3, q = idx & 7;
        *(uint4*)(Xsm + row * 136 + q * 8)      = *(const uint4*)(Alo + (size_t)(r0 + row) * 64 + q * 8);
        *(uint4*)(Xsm + row * 136 + 64 + q * 8) = *(const uint4*)(Ahi + (size_t)(r0 + row) * 128 + q * 8);
    }
    #pragma unroll
    for (int it = 0; it < 8; ++it){
        int idx = tid + it * 256;       // 2048 = 128 rows x 16 uint4
        int row = idx >> 4, q = idx & 15;
        *(uint4*)(Wsm + row * 136 + q * 8) = *(const uint4*)(Wt + (size_t)row * 128 + q * 8);
    }
}

__device__ __forceinline__ void mfma128_compute(const __half* Xsm, const __half* Wsm,
        int tid, floatx4 (&acc)[2][4]){
    const int wv = tid >> 6, lane = tid & 63, lr = lane & 15, lh = lane >> 4;
    const int rw = (wv >> 1) * 32;
    const int cw = (wv & 1) * 64;
    #pragma unroll
    for (int t = 0; t < 2; ++t)
        #pragma unroll
        for (int ct = 0; ct < 4; ++ct) acc[t][ct] = (floatx4){0.f, 0.f, 0.f, 0.f};
    #pragma unroll
    for (int s = 0; s < 4; ++s){
        int kb = s * 32 + lh * 8;
        half8 a0 = *(const half8*)(Xsm + (rw + lr) * 136 + kb);
        half8 a1 = *(const half8*)(Xsm + (rw + 16 + lr) * 136 + kb);
        #pragma unroll
        for (int ct = 0; ct < 4; ++ct){
            half8 b = *(const half8*)(Wsm + (cw + ct * 16 + lr) * 136 + kb);
            acc[0][ct] = __builtin_amdgcn_mfma_f32_16x16x32_f16(a0, b, acc[0][ct], 0, 0, 0);
            acc[1][ct] = __builtin_amdgcn_mfma_f32_16x16x32_f16(a1, b, acc[1][ct], 0, 0, 0);
        }
    }
}

// ---------------- layer-2 GEMM (split-A, dinv-scaled, to global) ----------------
__global__ __launch_bounds__(256) void k_mfma_sp(const __half* __restrict__ Alo,
        const __half* __restrict__ Ahi, const __half* __restrict__ Wt,
        const float* __restrict__ dinv, __half* __restrict__ Y){
    __shared__ __half Xsm[64 * 136];
    __shared__ __half Wsm[128 * 136];
    __shared__ float dvs[64];
    const int r0 = blockIdx.x * 64;
    const int tid = threadIdx.x;
    mfma128_stage(Alo, Ahi, Wt, Xsm, Wsm, r0, tid);
    if (tid < 64) dvs[tid] = dinv[r0 + tid];
    __syncthreads();
    floatx4 acc[2][4];
    mfma128_compute(Xsm, Wsm, tid, acc);
    const int wv = tid >> 6, lane = tid & 63, lr = lane & 15, lh = lane >> 4;
    const int rw = (wv >> 1) * 32, cw = (wv & 1) * 64;
    #pragma unroll
    for (int ct = 0; ct < 4; ++ct){
        int col = cw + ct * 16 + lr;
        #pragma unroll
        for (int t = 0; t < 2; ++t)
            #pragma unroll
            for (int reg = 0; reg < 4; ++reg){
                int rl = rw + t * 16 + lh * 4 + reg;
                Y[(size_t)(r0 + rl) * 128 + col] = __float2half(acc[t][ct][reg] * dvs[rl]);
            }
    }
}

// ---------------- fused K-GEMM + scores: st[b][k][i] = K_row . Q[b][i] ----------------
__global__ __launch_bounds__(256) void k_kscores(const __half* __restrict__ Alo,
        const __half* __restrict__ Ahi, const __half* __restrict__ Wt,
        const float* __restrict__ bias, const float* __restrict__ Qb,
        float* __restrict__ st){
    __shared__ __half Xsm[64 * 136];
    __shared__ __half Wsm[128 * 136];
    __shared__ __half Kbuf[64 * 136];
    __shared__ float Qs[8][132];
    const int r0 = blockIdx.x * 64;
    const int b  = r0 >> 10;
    const int tid = threadIdx.x;
    mfma128_stage(Alo, Ahi, Wt, Xsm, Wsm, r0, tid);
    #pragma unroll
    for (int it = 0; it < 4; ++it){
        int idx = tid + it * 256;       // 1024
        Qs[idx >> 7][idx & 127] = Qb[(size_t)(b * 8 + (idx >> 7)) * 128 + (idx & 127)];
    }
    __syncthreads();
    floatx4 acc[2][4];
    mfma128_compute(Xsm, Wsm, tid, acc);
    const int wv = tid >> 6, lane = tid & 63, lr = lane & 15, lh = lane >> 4;
    const int rw = (wv >> 1) * 32, cw = (wv & 1) * 64;
    #pragma unroll
    for (int ct = 0; ct < 4; ++ct){
        int col = cw + ct * 16 + lr;
        float bv = bias[col];
        #pragma unroll
        for (int t = 0; t < 2; ++t)
            #pragma unroll
            for (int reg = 0; reg < 4; ++reg){
                int rl = rw + t * 16 + lh * 4 + reg;
                Kbuf[rl * 136 + col] = __float2half(acc[t][ct][reg] + bv);
            }
    }
    __syncthreads();
    // scores: 512 dot-products (64 rows x 8 queries), 2 per thread
    #pragma unroll
    for (int p = 0; p < 2; ++p){
        int idx = tid + p * 256;
        int k = idx >> 3, i = idx & 7;
        const __half2* kr = (const __half2*)(Kbuf + k * 136);
        float a = 0.f;
        #pragma unroll 8
        for (int c2 = 0; c2 < 64; ++c2){
            float2 kf = __half22float2(kr[c2]);
            a += kf.x * Qs[i][2 * c2] + kf.y * Qs[i][2 * c2 + 1];
        }
        st[(size_t)b * 8192 + (size_t)((r0 & 1023) + k) * 8 + i] = a;
    }
}

// ---------------- Opart addressing: f32 partials packed into B0[:,64:128] ----------------
__device__ __forceinline__ float* opart_ptr(__half* B0, size_t L){
    return (float*)(B0 + (L >> 5) * 128 + 64) + (L & 31);
}

// ---------------- fused V-GEMM + partial PV ----------------
__global__ __launch_bounds__(256) void k_vpv(const __half* __restrict__ Alo,
        const __half* __restrict__ Ahi, const __half* __restrict__ Wt,
        const float* __restrict__ bias, const float* __restrict__ st,
        __half* __restrict__ B0op){
    __shared__ __half Xsm[64 * 136];
    __shared__ __half Wsm[128 * 136];
    __shared__ __half Vt[128 * 74];     // transposed V: [col][row]
    __shared__ float at[64][8];
    const int r0 = blockIdx.x * 64;
    const int b  = r0 >> 10;
    const int tid = threadIdx.x;
    mfma128_stage(Alo, Ahi, Wt, Xsm, Wsm, r0, tid);
    #pragma unroll
    for (int it = 0; it < 2; ++it){
        int idx = tid + it * 256;       // 512
        int k = idx >> 3, i = idx & 7;
        at[k][i] = st[(size_t)b * 8192 + (size_t)((r0 & 1023) + k) * 8 + i];
    }
    __syncthreads();
    floatx4 acc[2][4];
    mfma128_compute(Xsm, Wsm, tid, acc);
    const int wv = tid >> 6, lane = tid & 63, lr = lane & 15, lh = lane >> 4;
    const int rw = (wv >> 1) * 32, cw = (wv & 1) * 64;
    #pragma unroll
    for (int ct = 0; ct < 4; ++ct){
        int col = cw + ct * 16 + lr;
        float bv = bias[col];
        #pragma unroll
        for (int t = 0; t < 2; ++t)
            #pragma unroll
            for (int reg = 0; reg < 4; ++reg){
                int rl = rw + t * 16 + lh * 4 + reg;
                Vt[col * 74 + rl] = __float2half(acc[t][ct][reg] + bv);
            }
    }
    __syncthreads();
    // partial PV: O_part[i][c] = sum_{k<64} at[k][i] * V[k][c]
    int i = tid >> 5, c2 = tid & 31;
    const __half2* v0 = (const __half2*)(Vt + (2 * c2) * 74);
    const __half2* v1 = (const __half2*)(Vt + (2 * c2 + 1) * 74);
    const __half2* v2 = (const __half2*)(Vt + (2 * c2 + 64) * 74);
    const __half2* v3 = (const __half2*)(Vt + (2 * c2 + 65) * 74);
    float a0 = 0.f, a1 = 0.f, a2 = 0.f, a3 = 0.f;
    for (int k2 = 0; k2 < 32; ++k2){
        float w0 = at[2 * k2][i], w1 = at[2 * k2 + 1][i];
        float2 f0 = __half22float2(v0[k2]); a0 += w0 * f0.x + w1 * f0.y;
        float2 f1 = __half22float2(v1[k2]); a1 += w0 * f1.x + w1 * f1.y;
        float2 f2 = __half22float2(v2[k2]); a2 += w0 * f2.x + w1 * f2.y;
        float2 f3 = __half22float2(v3[k2]); a3 += w0 * f3.x + w1 * f3.y;
    }
    size_t base = ((size_t)blockIdx.x * 8 + i) * 128;
    *opart_ptr(B0op, base + 2 * c2)      = a0;
    *opart_ptr(B0op, base + 2 * c2 + 1)  = a1;
    *opart_ptr(B0op, base + 2 * c2 + 64) = a2;
    *opart_ptr(B0op, base + 2 * c2 + 65) = a3;
}

// ---------------- reduce partials: pvout[b,i,c] = sum_{j<16} Opart[b*16+j][i][c] ----
__global__ void k_oreduce(const __half* __restrict__ B0op, float* __restrict__ pvout){
    int idx = blockIdx.x * 256 + threadIdx.x;   // 262144
    int bi = idx >> 7, c = idx & 127;
    int b = bi >> 3, i = bi & 7;
    float s = 0.f;
    #pragma unroll
    for (int j = 0; j < 16; ++j){
        size_t L = (((size_t)(b * 16 + j) * 8 + i) << 7) + c;
        s += *((const float*)(B0op + (L >> 5) * 128 + 64) + (L & 31));
    }
    pvout[idx] = s;
}

// ---------------- MFMA layer1: x f32 [N,32] @ Wt1, scaled by dinv -> B0 f16 [N,128] ----
__global__ __launch_bounds__(256) void k_mfma_l1(const float* __restrict__ X,
        const __half* __restrict__ Wt, const float* __restrict__ dinv,
        __half* __restrict__ Y){
    constexpr int KD = 32, PD = 40, CO = 128;
    __shared__ __half Xs[64 * PD];
    __shared__ __half Ws[CO * PD];
    __shared__ float dvs[64];
    const int r0 = blockIdx.x * 64;
    const int tid = threadIdx.x;
    #pragma unroll
    for (int it = 0; it < 2; ++it){
        int idx = tid + it * 256;
        int row = idx >> 3, q = idx & 7;
        float4 f = ((const float4*)(X + (size_t)(r0 + row) * KD))[q];
        *(__half2*)(Xs + row * PD + q * 4)     = __floats2half2_rn(f.x, f.y);
        *(__half2*)(Xs + row * PD + q * 4 + 2) = __floats2half2_rn(f.z, f.w);
    }
    #pragma unroll
    for (int it = 0; it < 2; ++it){
        int idx = tid + it * 256;
        int row = idx >> 2, q = idx & 3;
        uint4 u = ((const uint4*)(Wt + (size_t)row * KD))[q];
        *(uint4*)(Ws + row * PD + q * 8) = u;
    }
    if (tid < 64) dvs[tid] = dinv[r0 + tid];
    __syncthreads();
    const int wv = tid >> 6, lane = tid & 63, lr = lane & 15, lh = lane >> 4;
    const int rw = (wv >> 1) * 32;
    const int cw = (wv & 1) * 64;
    floatx4 acc[2][4];
    #pragma unroll
    for (int t = 0; t < 2; ++t)
        #pragma unroll
        for (int ct = 0; ct < 4; ++ct) acc[t][ct] = (floatx4){0.f, 0.f, 0.f, 0.f};
    int kb = lh * 8;
    half8 a0 = *(const half8*)(Xs + (rw + lr) * PD + kb);
    half8 a1 = *(const half8*)(Xs + (rw + 16 + lr) * PD + kb);
    #pragma unroll
    for (int ct = 0; ct < 4; ++ct){
        half8 b = *(const half8*)(Ws + (cw + ct * 16 + lr) * PD + kb);
        acc[0][ct] = __builtin_amdgcn_mfma_f32_16x16x32_f16(a0, b, acc[0][ct], 0, 0, 0);
        acc[1][ct] = __builtin_amdgcn_mfma_f32_16x16x32_f16(a1, b, acc[1][ct], 0, 0, 0);
    }
    #pragma unroll
    for (int ct = 0; ct < 4; ++ct){
        int col = cw + ct * 16 + lr;
        #pragma unroll
        for (int t = 0; t < 2; ++t)
            #pragma unroll
            for (int reg = 0; reg < 4; ++reg){
                int rl = rw + t * 16 + lh * 4 + reg;
                Y[(size_t)(r0 + rl) * CO + col] = __float2half(acc[t][ct][reg] * dvs[rl]);
            }
    }
}

// ---------------- fused gather + bias + selu, 64-ch, ILP-8, pre-scaled rows ----------------
__global__ __launch_bounds__(256) void k_gather64(const int* __restrict__ indptr,
        const int* __restrict__ esrc, const float* __restrict__ dinv,
        const __half2* __restrict__ Xs, int xs2,
        const float* __restrict__ bias, int boff,
        __half2* __restrict__ Yo, int ys2){
    int t = blockIdx.x * blockDim.x + threadIdx.x;
    int node = t >> 5;
    if (node >= NNODES) return;
    int c2 = t & 31;
    float dn = dinv[node];
    int beg = indptr[node], end = indptr[node + 1];
    float2 a = __half22float2(Xs[(size_t)node * xs2 + c2]);
    float ax = a.x, ay = a.y;
    int j = beg;
    for (; j + 8 <= end; j += 8){
        int s0 = esrc[j],   s1 = esrc[j+1], s2 = esrc[j+2], s3 = esrc[j+3];
        int s4 = esrc[j+4], s5 = esrc[j+5], s6 = esrc[j+6], s7 = esrc[j+7];
        float2 g0 = __half22float2(Xs[(size_t)s0 * xs2 + c2]);
        float2 g1 = __half22float2(Xs[(size_t)s1 * xs2 + c2]);
        float2 g2 = __half22float2(Xs[(size_t)s2 * xs2 + c2]);
        float2 g3 = __half22float2(Xs[(size_t)s3 * xs2 + c2]);
        float2 g4 = __half22float2(Xs[(size_t)s4 * xs2 + c2]);
        float2 g5 = __half22float2(Xs[(size_t)s5 * xs2 + c2]);
        float2 g6 = __half22float2(Xs[(size_t)s6 * xs2 + c2]);
        float2 g7 = __half22float2(Xs[(size_t)s7 * xs2 + c2]);
        ax += ((g0.x + g1.x) + (g2.x + g3.x)) + ((g4.x + g5.x) + (g6.x + g7.x));
        ay += ((g0.y + g1.y) + (g2.y + g3.y)) + ((g4.y + g5.y) + (g6.y + g7.y));
    }
    for (; j + 4 <= end; j += 4){
        int s0 = esrc[j], s1 = esrc[j+1], s2 = esrc[j+2], s3 = esrc[j+3];
        float2 g0 = __half22float2(Xs[(size_t)s0 * xs2 + c2]);
        float2 g1 = __half22float2(Xs[(size_t)s1 * xs2 + c2]);
        float2 g2 = __half22float2(Xs[(size_t)s2 * xs2 + c2]);
        float2 g3 = __half22float2(Xs[(size_t)s3 * xs2 + c2]);
        ax += (g0.x + g1.x) + (g2.x + g3.x);
        ay += (g0.y + g1.y) + (g2.y + g3.y);
    }
    for (; j < end; ++j){
        float2 g = __half22float2(Xs[(size_t)esrc[j] * xs2 + c2]);
        ax += g.x; ay += g.y;
    }
    ax = selu_f(ax * dn + bias[boff + 2 * c2]);
    ay = selu_f(ay * dn + bias[boff + 2 * c2 + 1]);
    Yo[(size_t)node * ys2 + c2] = __floats2half2_rn(ax, ay);
}

// ---------------- per-graph masked-node selection + shuffle ----------------
__global__ void k_qnode(const float* __restrict__ x, const int* __restrict__ shuf,
                        int* __restrict__ qnode){
    int b = blockIdx.x;
    int lane = threadIdx.x;   // 64
    __shared__ int list[MAXN];
    int localIdx[16];
    int cnt = 0;
    #pragma unroll
    for (int j = 0; j < 16; ++j){
        int node = lane * 16 + j;
        float m = x[(size_t)(b * NNPG + node) * INCH + (INCH - 3)];
        if (m > 0.5f){ if (cnt < 16) localIdx[cnt] = node; cnt++; }
    }
    int pref = cnt;
    #pragma unroll
    for (int off = 1; off < 64; off <<= 1){
        int v = __shfl_up(pref, off);
        if (lane >= off) pref += v;
    }
    pref -= cnt;
    for (int t = 0; t < cnt; ++t){
        int pos = pref + t;
        if (pos < MAXN) list[pos] = localIdx[t];
    }
    __syncthreads();
    if (lane < MAXN){
        int sidx = shuf[b * MAXN + lane];
        qnode[b * MAXN + lane] = b * NNPG + list[sidx];
    }
}

// ---------------- Q = (h2[qnode] @ Wq + bq) / sqrt(H); h2 split in B1/B0 ----------------
__global__ __launch_bounds__(128) void k_qgemm(const __half* __restrict__ hLo,
        const __half* __restrict__ hHi, const int* __restrict__ qnode,
        const float* __restrict__ Wq, const float* __restrict__ bq, float* __restrict__ Q){
    __shared__ float hs[HD];
    int row = blockIdx.x;
    int c = threadIdx.x;
    int node = qnode[row];
    if (c < 64) hs[c] = __half2float(hLo[(size_t)node * 64 + c]);
    else        hs[c] = __half2float(hHi[(size_t)node * 128 + (c - 64)]);
    __syncthreads();
    float acc = bq[c];
    for (int k = 0; k < HD; ++k) acc += hs[k] * Wq[k * HD + c];
    Q[row * HD + c] = acc * 0.08838834764831845f;
}

// ---------------- softmax over k for each (b,i); scores_t [b][k][8] in-place ----------------
__global__ __launch_bounds__(256) void k_softmax2(float* __restrict__ st){
    int b = blockIdx.x, tid = threadIdx.x;
    int wv = tid >> 6, lane = tid & 63;
    float* base = st + (size_t)b * NNPG * MAXN;
    float v[4][MAXN];
    #pragma unroll
    for (int r = 0; r < 4; ++r){
        int k = tid + r * 256;
        float4 a0 = ((const float4*)(base + k * MAXN))[0];
        float4 a1 = ((const float4*)(base + k * MAXN))[1];
        v[r][0]=a0.x; v[r][1]=a0.y; v[r][2]=a0.z; v[r][3]=a0.w;
        v[r][4]=a1.x; v[r][5]=a1.y; v[r][6]=a1.z; v[r][7]=a1.w;
    }
    float m[MAXN];
    #pragma unroll
    for (int i = 0; i < MAXN; ++i)
        m[i] = fmaxf(fmaxf(v[0][i], v[1][i]), fmaxf(v[2][i], v[3][i]));
    #pragma unroll
    for (int off = 32; off; off >>= 1)
        #pragma unroll
        for (int i = 0; i < MAXN; ++i) m[i] = fmaxf(m[i], __shfl_xor(m[i], off));
    __shared__ float red[2][4][MAXN];
    if (lane == 0)
        #pragma unroll
        for (int i = 0; i < MAXN; ++i) red[0][wv][i] = m[i];
    __syncthreads();
    #pragma unroll
    for (int i = 0; i < MAXN; ++i)
        m[i] = fmaxf(fmaxf(red[0][0][i], red[0][1][i]), fmaxf(red[0][2][i], red[0][3][i]));
    float s[MAXN];
    #pragma unroll
    for (int i = 0; i < MAXN; ++i) s[i] = 0.f;
    #pragma unroll
    for (int r = 0; r < 4; ++r)
        #pragma unroll
        for (int i = 0; i < MAXN; ++i){
            v[r][i] = expf(v[r][i] - m[i]);
            s[i] += v[r][i];
        }
    #pragma unroll
    for (int off = 32; off; off >>= 1)
        #pragma unroll
        for (int i = 0; i < MAXN; ++i) s[i] += __shfl_xor(s[i], off);
    if (lane == 0)
        #pragma unroll
        for (int i = 0; i < MAXN; ++i) red[1][wv][i] = s[i];
    __syncthreads();
    #pragma unroll
    for (int i = 0; i < MAXN; ++i){
        float tot = red[1][0][i] + red[1][1][i] + red[1][2][i] + red[1][3][i];
        s[i] = 1.0f / tot;
    }
    #pragma unroll
    for (int r = 0; r < 4; ++r){
        int k = tid + r * 256;
        float4 a0 = make_float4(v[r][0]*s[0], v[r][1]*s[1], v[r][2]*s[2], v[r][3]*s[3]);
        float4 a1 = make_float4(v[r][4]*s[4], v[r][5]*s[5], v[r][6]*s[6], v[r][7]*s[7]);
        ((float4*)(base + k * MAXN))[0] = a0;
        ((float4*)(base + k * MAXN))[1] = a1;
    }
}

// ---------------- tail: Wo+bo+selu then Wfc+bfc -> out[b][8] ----------------
__global__ __launch_bounds__(256) void k_tail(const float* __restrict__ pvout,
        const float* __restrict__ Wo, const float* __restrict__ bo,
        const float* __restrict__ Wfc, const float* __restrict__ bfc,
        float* __restrict__ out){
    int b = blockIdx.x;
    int tid = threadIdx.x;
    __shared__ float pv[MAXN * HD];
    __shared__ float sol[MAXN * HD];
    __shared__ float red[64];
    for (int idx = tid; idx < MAXN * HD / 4; idx += 256)
        ((float4*)pv)[idx] = ((const float4*)(pvout + (size_t)b * MAXN * HD))[idx];
    __syncthreads();
    int c = tid & 127;
    int grp = tid >> 7;
    float bb = bo[c];
    float acc[4];
    #pragma unroll
    for (int j = 0; j < 4; ++j) acc[j] = bb;
    for (int k = 0; k < HD; ++k){
        float w = Wo[k * HD + c];
        #pragma unroll
        for (int j = 0; j < 4; ++j) acc[j] += pv[(grp*4 + j) * HD + k] * w;
    }
    #pragma unroll
    for (int j = 0; j < 4; ++j) sol[(grp*4 + j) * HD + c] = selu_f(acc[j]);
    __syncthreads();
    if (tid < 64){
        int j = tid & 7;
        int part = tid >> 3;
        float p = 0.f;
        for (int m = part * 128; m < part * 128 + 128; ++m) p += sol[m] * Wfc[m * MAXN + j];
        red[tid] = p;
    }
    __syncthreads();
    if (tid < MAXN){
        float s = bfc[tid];
        #pragma unroll
        for (int part = 0; part < 8; ++part) s += red[part * 8 + tid];
        out[b * MAXN + tid] = s;
    }
}

extern "C" void kernel_launch(void* const* d_in, const int* in_sizes, int n_in,
                              void* d_out, int out_size, void* d_ws, size_t ws_size,
                              hipStream_t stream) {
    const float* x    = (const float*)d_in[0];
    const int*   edge = (const int*)d_in[1];
    const int*   shuf = (const int*)d_in[2];
    const float* W1   = (const float*)d_in[3];
    const float* b1   = (const float*)d_in[4];
    const float* W2   = (const float*)d_in[5];
    const float* b2   = (const float*)d_in[6];
    const float* Wq   = (const float*)d_in[7];
    const float* bq   = (const float*)d_in[8];
    const float* Wk   = (const float*)d_in[9];
    const float* bk   = (const float*)d_in[10];
    const float* Wv   = (const float*)d_in[11];
    const float* bv   = (const float*)d_in[12];
    const float* Wo   = (const float*)d_in[13];
    const float* bo   = (const float*)d_in[14];
    const float* Wfc  = (const float*)d_in[15];
    const float* bfc  = (const float*)d_in[16];
    float* out = (float*)d_out;

    // workspace layout — ~107.1 MiB
    char* w = (char*)d_ws;
    __half* B0    = (__half*)w;  w += (size_t)NNODES * HD * sizeof(__half);    // 64 MiB
    __half* B1    = (__half*)w;  w += (size_t)NNODES * 64 * sizeof(__half);    // 32 MiB
    float*  R1    = (float*)w;   w += (size_t)NNODES * sizeof(float);          // 1 MiB: dinv (pvout after)
    int*    R2    = (int*)w;     w += (size_t)NNODES * sizeof(int);            // 1 MiB: deg/cursor (Qb after)
    int*    indptr= (int*)w;     w += ((size_t)NNODES + 64) * sizeof(int);
    int*    bsum  = (int*)w;     w += 1024;
    int*    qnode = (int*)w;     w += 8192;
    __half* Wt1   = (__half*)w;  w += 128 * INCH * sizeof(__half);
    __half* Wt2   = (__half*)w;  w += 128 * HD * sizeof(__half);
    __half* Wtk   = (__half*)w;  w += 128 * HD * sizeof(__half);
    __half* Wtv   = (__half*)w;  w += 128 * HD * sizeof(__half);
    char*   U     = w;           w += (size_t)NGRAPH * MAXN * NNPG * sizeof(float); // 8 MiB
    size_t need = (size_t)(w - (char*)d_ws);
    if (ws_size < need) return;

    float* dinv  = R1;
    float* pvout = R1;            // reused after layer-2 gathers
    int*   degcur= R2;
    float* Qb    = (float*)R2;    // reused after CSR build
    int*   esrc  = (int*)U;       // GNN phase
    float* st    = (float*)U;     // attention phase

    const int* srcp = edge;
    const int* dstp = edge + NEDGE;

    // ---- CSR build ----
    hipMemsetAsync(degcur, 0, NNODES * sizeof(int), stream);
    k_deg<<<NEDGE / 1024, 256, 0, stream>>>(dstp, degcur);
    k_dinv<<<NNODES / 256, 256, 0, stream>>>(degcur, dinv);
    k_scan1<<<256, 256, 0, stream>>>(degcur, indptr, bsum);
    k_scan2<<<1, 256, 0, stream>>>(bsum);
    k_scan3<<<256, 256, 0, stream>>>(indptr, bsum);
    hipMemsetAsync(degcur, 0, NNODES * sizeof(int), stream);
    k_fill<<<NEDGE / 1024, 256, 0, stream>>>(srcp, dstp, indptr, degcur, esrc);

    // ---- weight prep ----
    k_wprep<<<(128 * INCH) / 256, 256, 0, stream>>>(W1, Wt1, INCH);
    k_wprep<<<(128 * HD) / 256, 256, 0, stream>>>(W2, Wt2, HD);
    k_wprep<<<(128 * HD) / 256, 256, 0, stream>>>(Wk, Wtk, HD);
    k_wprep<<<(128 * HD) / 256, 256, 0, stream>>>(Wv, Wtv, HD);

    const int gBlocks = (NNODES * 32) / 256;   // gather grid

    // ---- layer 1: scaled xw1 full in B0; gather h0->B1, h1->B0[:,0:64] ----
    k_mfma_l1<<<NNODES / 64, 256, 0, stream>>>(x, Wt1, dinv, B0);
    k_gather64<<<gBlocks, 256, 0, stream>>>(indptr, esrc, dinv,
            (const __half2*)B0, 64, b1, 0, (__half2*)B1, 32);
    k_gather64<<<gBlocks, 256, 0, stream>>>(indptr, esrc, dinv,
            (const __half2*)(B0 + 64), 64, b1, 64, (__half2*)B0, 64);
    // ---- layer 2: split-A GEMM -> scaled xw2 full in B0 (in-place); gathers ----
    k_mfma_sp<<<NNODES / 64, 256, 0, stream>>>(B1, B0, Wt2, dinv, B0);
    k_gather64<<<gBlocks, 256, 0, stream>>>(indptr, esrc, dinv,
            (const __half2*)B0, 64, b2, 0, (__half2*)B1, 32);
    k_gather64<<<gBlocks, 256, 0, stream>>>(indptr, esrc, dinv,
            (const __half2*)(B0 + 64), 64, b2, 64, (__half2*)B0, 64);
    // h2: cols 0-63 in B1 (stride 64), cols 64-127 in B0[:,0:64] (stride 128)

    // ---- attention ----
    k_qnode<<<NGRAPH, 64, 0, stream>>>(x, shuf, qnode);
    k_qgemm<<<NGRAPH * MAXN, 128, 0, stream>>>(B1, B0, qnode, Wq, bq, Qb);

    // fused K-GEMM + scores (K lives only in LDS)
    k_kscores<<<NNODES / 64, 256, 0, stream>>>(B1, B0, Wtk, bk, Qb, st);
    k_softmax2<<<NGRAPH, 256, 0, stream>>>(st);
    // fused V-GEMM + partial PV -> Opart in dead B0[:,64:128] region
    k_vpv<<<NNODES / 64, 256, 0, stream>>>(B1, B0, Wtv, bv, st, B0);
    k_oreduce<<<(NGRAPH * MAXN * HD) / 256, 256, 0, stream>>>(B0, pvout);

    k_tail<<<NGRAPH, 256, 0, stream>>>(pvout, Wo, bo, Wfc, bfc, out);
}

// Round 8
// 674.112 us; speedup vs baseline: 23.3111x; 1.2615x over previous
//
#include <hip/hip_runtime.h>
#include <hip/hip_fp16.h>
#include <math.h>

#define NNODES 262144   // total nodes
#define NNPG   1024     // nodes per graph
#define NGRAPH 256      // graphs
#define INCH   32       // in channels
#define HD     128      // hidden
#define MAXN   8
#define NEDGE  2097152

using half8  = __attribute__((ext_vector_type(8))) _Float16;
using floatx4 = __attribute__((ext_vector_type(4))) float;

__device__ __forceinline__ float selu_f(float v){
    const float alpha = 1.6732632423543772f;
    const float scale = 1.0507009873554805f;
    return v > 0.f ? scale * v : scale * alpha * expm1f(v);
}

// ---------------- degree + per-edge rank (1 edge/thread for max TLP) ----------------
__global__ void k_deg(const int* __restrict__ dst, int* __restrict__ deg,
                      int* __restrict__ ecur){
    int e = blockIdx.x * blockDim.x + threadIdx.x;
    ecur[e] = atomicAdd(&deg[dst[e]], 1);
}

__global__ void k_dinv(const int* __restrict__ deg, float* __restrict__ dinv){
    int i = blockIdx.x * blockDim.x + threadIdx.x;
    if (i < NNODES) dinv[i] = rsqrtf((float)deg[i] + 1.0f);
}

// ---------------- prefix sum (3-pass) ----------------
__global__ __launch_bounds__(256) void k_scan1(const int* __restrict__ deg,
        int* __restrict__ indptr, int* __restrict__ bsum){
    int bid = blockIdx.x, tid = threadIdx.x;
    int4 v = ((const int4*)deg)[bid * 256 + tid];
    int s = v.x + v.y + v.z + v.w;
    int lane = tid & 63;
    int p = s;
    #pragma unroll
    for (int off = 1; off < 64; off <<= 1){
        int u = __shfl_up(p, off);
        if (lane >= off) p += u;
    }
    __shared__ int ws[4];
    if (lane == 63) ws[tid >> 6] = p;
    __syncthreads();
    int w = tid >> 6, wo = 0;
    if (w > 0) wo = ws[0];
    if (w > 1) wo += ws[1];
    if (w > 2) wo += ws[2];
    int excl = wo + p - s;
    int base = bid * 1024 + tid * 4;
    indptr[base + 0] = excl;
    indptr[base + 1] = excl + v.x;
    indptr[base + 2] = excl + v.x + v.y;
    indptr[base + 3] = excl + v.x + v.y + v.z;
    if (tid == 255) bsum[bid] = excl + s;
}

__global__ __launch_bounds__(256) void k_scan2(int* __restrict__ bsum){
    int tid = threadIdx.x;
    int v = bsum[tid];
    int lane = tid & 63;
    int p = v;
    #pragma unroll
    for (int off = 1; off < 64; off <<= 1){
        int u = __shfl_up(p, off);
        if (lane >= off) p += u;
    }
    __shared__ int ws[4];
    if (lane == 63) ws[tid >> 6] = p;
    __syncthreads();
    int w = tid >> 6, wo = 0;
    if (w > 0) wo = ws[0];
    if (w > 1) wo += ws[1];
    if (w > 2) wo += ws[2];
    bsum[tid] = wo + p - v;
}

__global__ __launch_bounds__(256) void k_scan3(int* __restrict__ indptr,
        const int* __restrict__ bsum){
    int bid = blockIdx.x;
    int off = bsum[bid];
    int4* p = (int4*)indptr + bid * 256 + threadIdx.x;
    int4 v = *p;
    v.x += off; v.y += off; v.z += off; v.w += off;
    *p = v;
    if (bid == 0 && threadIdx.x == 0) indptr[NNODES] = NEDGE;
}

// ---------------- fill CSR: atomic-free (rank precomputed in deg pass) ----------------
__global__ void k_fill(const int* __restrict__ src, const int* __restrict__ dst,
        const int* __restrict__ indptr, const int* __restrict__ ecur,
        int* __restrict__ esrc){
    int e = blockIdx.x * blockDim.x + threadIdx.x;
    esrc[indptr[dst[e]] + ecur[e]] = src[e];
}

// ---------------- W prep: W f32 [KD][128] -> Wt f16 [128][KD] ----------------
__global__ void k_wprep(const float* __restrict__ W, __half* __restrict__ Wt, int KD){
    int idx = blockIdx.x * 256 + threadIdx.x;
    int c = idx / KD, k = idx - c * KD;
    Wt[idx] = __float2half(W[k * 128 + c]);
}

// ---------------- shared MFMA core: split-A [64 rows,128] @ Wt[128][128] -> acc ----
__device__ __forceinline__ void mfma128_stage(const __half* __restrict__ Alo,
        const __half* __restrict__ Ahi, const __half* __restrict__ Wt,
        __half* Xsm, __half* Wsm, int r0, int tid){
    #pragma unroll
    for (int it = 0; it < 2; ++it){
        int idx = tid + it * 256;       // 512 = 64 rows x 8 uint4
        int row = idx >> 3, q = idx & 7;
        *(uint4*)(Xsm + row * 136 + q * 8)      = *(const uint4*)(Alo + (size_t)(r0 + row) * 64 + q * 8);
        *(uint4*)(Xsm + row * 136 + 64 + q * 8) = *(const uint4*)(Ahi + (size_t)(r0 + row) * 128 + q * 8);
    }
    #pragma unroll
    for (int it = 0; it < 8; ++it){
        int idx = tid + it * 256;       // 2048 = 128 rows x 16 uint4
        int row = idx >> 4, q = idx & 15;
        *(uint4*)(Wsm + row * 136 + q * 8) = *(const uint4*)(Wt + (size_t)row * 128 + q * 8);
    }
}

__device__ __forceinline__ void mfma128_compute(const __half* Xsm, const __half* Wsm,
        int tid, floatx4 (&acc)[2][4]){
    const int wv = tid >> 6, lane = tid & 63, lr = lane & 15, lh = lane >> 4;
    const int rw = (wv >> 1) * 32;
    const int cw = (wv & 1) * 64;
    #pragma unroll
    for (int t = 0; t < 2; ++t)
        #pragma unroll
        for (int ct = 0; ct < 4; ++ct) acc[t][ct] = (floatx4){0.f, 0.f, 0.f, 0.f};
    #pragma unroll
    for (int s = 0; s < 4; ++s){
        int kb = s * 32 + lh * 8;
        half8 a0 = *(const half8*)(Xsm + (rw + lr) * 136 + kb);
        half8 a1 = *(const half8*)(Xsm + (rw + 16 + lr) * 136 + kb);
        #pragma unroll
        for (int ct = 0; ct < 4; ++ct){
            half8 b = *(const half8*)(Wsm + (cw + ct * 16 + lr) * 136 + kb);
            acc[0][ct] = __builtin_amdgcn_mfma_f32_16x16x32_f16(a0, b, acc[0][ct], 0, 0, 0);
            acc[1][ct] = __builtin_amdgcn_mfma_f32_16x16x32_f16(a1, b, acc[1][ct], 0, 0, 0);
        }
    }
}

// ---------------- layer-2 GEMM (split-A, dinv-scaled, to global) ----------------
__global__ __launch_bounds__(256) void k_mfma_sp(const __half* __restrict__ Alo,
        const __half* __restrict__ Ahi, const __half* __restrict__ Wt,
        const float* __restrict__ dinv, __half* __restrict__ Y){
    __shared__ __half Xsm[64 * 136];
    __shared__ __half Wsm[128 * 136];
    __shared__ float dvs[64];
    const int r0 = blockIdx.x * 64;
    const int tid = threadIdx.x;
    mfma128_stage(Alo, Ahi, Wt, Xsm, Wsm, r0, tid);
    if (tid < 64) dvs[tid] = dinv[r0 + tid];
    __syncthreads();
    floatx4 acc[2][4];
    mfma128_compute(Xsm, Wsm, tid, acc);
    const int wv = tid >> 6, lane = tid & 63, lr = lane & 15, lh = lane >> 4;
    const int rw = (wv >> 1) * 32, cw = (wv & 1) * 64;
    #pragma unroll
    for (int ct = 0; ct < 4; ++ct){
        int col = cw + ct * 16 + lr;
        #pragma unroll
        for (int t = 0; t < 2; ++t)
            #pragma unroll
            for (int reg = 0; reg < 4; ++reg){
                int rl = rw + t * 16 + lh * 4 + reg;
                Y[(size_t)(r0 + rl) * 128 + col] = __float2half(acc[t][ct][reg] * dvs[rl]);
            }
    }
}

// ---------------- fused K-GEMM + scores: st[b][k][i] = K_row . Q[b][i] ----------------
__global__ __launch_bounds__(256) void k_kscores(const __half* __restrict__ Alo,
        const __half* __restrict__ Ahi, const __half* __restrict__ Wt,
        const float* __restrict__ bias, const float* __restrict__ Qb,
        float* __restrict__ st){
    __shared__ __half Xsm[64 * 136];
    __shared__ __half Wsm[128 * 136];
    __shared__ __half Kbuf[64 * 136];
    __shared__ float Qs[8][132];
    const int r0 = blockIdx.x * 64;
    const int b  = r0 >> 10;
    const int tid = threadIdx.x;
    mfma128_stage(Alo, Ahi, Wt, Xsm, Wsm, r0, tid);
    #pragma unroll
    for (int it = 0; it < 4; ++it){
        int idx = tid + it * 256;       // 1024
        Qs[idx >> 7][idx & 127] = Qb[(size_t)(b * 8 + (idx >> 7)) * 128 + (idx & 127)];
    }
    __syncthreads();
    floatx4 acc[2][4];
    mfma128_compute(Xsm, Wsm, tid, acc);
    const int wv = tid >> 6, lane = tid & 63, lr = lane & 15, lh = lane >> 4;
    const int rw = (wv >> 1) * 32, cw = (wv & 1) * 64;
    #pragma unroll
    for (int ct = 0; ct < 4; ++ct){
        int col = cw + ct * 16 + lr;
        float bv = bias[col];
        #pragma unroll
        for (int t = 0; t < 2; ++t)
            #pragma unroll
            for (int reg = 0; reg < 4; ++reg){
                int rl = rw + t * 16 + lh * 4 + reg;
                Kbuf[rl * 136 + col] = __float2half(acc[t][ct][reg] + bv);
            }
    }
    __syncthreads();
    // scores: 512 dot-products (64 rows x 8 queries), 2 per thread
    #pragma unroll
    for (int p = 0; p < 2; ++p){
        int idx = tid + p * 256;
        int k = idx >> 3, i = idx & 7;
        const __half2* kr = (const __half2*)(Kbuf + k * 136);
        float a = 0.f;
        #pragma unroll 8
        for (int c2 = 0; c2 < 64; ++c2){
            float2 kf = __half22float2(kr[c2]);
            a += kf.x * Qs[i][2 * c2] + kf.y * Qs[i][2 * c2 + 1];
        }
        st[(size_t)b * 8192 + (size_t)((r0 & 1023) + k) * 8 + i] = a;
    }
}

// ---------------- Opart addressing: f32 partials packed into B0[:,64:128] ----------------
__device__ __forceinline__ float* opart_ptr(__half* B0, size_t L){
    return (float*)(B0 + (L >> 5) * 128 + 64) + (L & 31);
}

// ---------------- fused V-GEMM + partial PV ----------------
__global__ __launch_bounds__(256) void k_vpv(const __half* __restrict__ Alo,
        const __half* __restrict__ Ahi, const __half* __restrict__ Wt,
        const float* __restrict__ bias, const float* __restrict__ st,
        __half* __restrict__ B0op){
    __shared__ __half Xsm[64 * 136];
    __shared__ __half Wsm[128 * 136];
    __shared__ __half Vt[128 * 74];     // transposed V: [col][row]
    __shared__ float at[64][8];
    const int r0 = blockIdx.x * 64;
    const int b  = r0 >> 10;
    const int tid = threadIdx.x;
    mfma128_stage(Alo, Ahi, Wt, Xsm, Wsm, r0, tid);
    #pragma unroll
    for (int it = 0; it < 2; ++it){
        int idx = tid + it * 256;       // 512
        int k = idx >> 3, i = idx & 7;
        at[k][i] = st[(size_t)b * 8192 + (size_t)((r0 & 1023) + k) * 8 + i];
    }
    __syncthreads();
    floatx4 acc[2][4];
    mfma128_compute(Xsm, Wsm, tid, acc);
    const int wv = tid >> 6, lane = tid & 63, lr = lane & 15, lh = lane >> 4;
    const int rw = (wv >> 1) * 32, cw = (wv & 1) * 64;
    #pragma unroll
    for (int ct = 0; ct < 4; ++ct){
        int col = cw + ct * 16 + lr;
        float bv = bias[col];
        #pragma unroll
        for (int t = 0; t < 2; ++t)
            #pragma unroll
            for (int reg = 0; reg < 4; ++reg){
                int rl = rw + t * 16 + lh * 4 + reg;
                Vt[col * 74 + rl] = __float2half(acc[t][ct][reg] + bv);
            }
    }
    __syncthreads();
    // partial PV: O_part[i][c] = sum_{k<64} at[k][i] * V[k][c]
    int i = tid >> 5, c2 = tid & 31;
    const __half2* v0 = (const __half2*)(Vt + (2 * c2) * 74);
    const __half2* v1 = (const __half2*)(Vt + (2 * c2 + 1) * 74);
    const __half2* v2 = (const __half2*)(Vt + (2 * c2 + 64) * 74);
    const __half2* v3 = (const __half2*)(Vt + (2 * c2 + 65) * 74);
    float a0 = 0.f, a1 = 0.f, a2 = 0.f, a3 = 0.f;
    for (int k2 = 0; k2 < 32; ++k2){
        float w0 = at[2 * k2][i], w1 = at[2 * k2 + 1][i];
        float2 f0 = __half22float2(v0[k2]); a0 += w0 * f0.x + w1 * f0.y;
        float2 f1 = __half22float2(v1[k2]); a1 += w0 * f1.x + w1 * f1.y;
        float2 f2 = __half22float2(v2[k2]); a2 += w0 * f2.x + w1 * f2.y;
        float2 f3 = __half22float2(v3[k2]); a3 += w0 * f3.x + w1 * f3.y;
    }
    size_t base = ((size_t)blockIdx.x * 8 + i) * 128;
    *opart_ptr(B0op, base + 2 * c2)      = a0;
    *opart_ptr(B0op, base + 2 * c2 + 1)  = a1;
    *opart_ptr(B0op, base + 2 * c2 + 64) = a2;
    *opart_ptr(B0op, base + 2 * c2 + 65) = a3;
}

// ---------------- reduce partials: pvout[b,i,c] = sum_{j<16} Opart[b*16+j][i][c] ----
__global__ void k_oreduce(const __half* __restrict__ B0op, float* __restrict__ pvout){
    int idx = blockIdx.x * 256 + threadIdx.x;   // 262144
    int bi = idx >> 7, c = idx & 127;
    int b = bi >> 3, i = bi & 7;
    float s = 0.f;
    #pragma unroll
    for (int j = 0; j < 16; ++j){
        size_t L = (((size_t)(b * 16 + j) * 8 + i) << 7) + c;
        s += *((const float*)(B0op + (L >> 5) * 128 + 64) + (L & 31));
    }
    pvout[idx] = s;
}

// ---------------- MFMA layer1: x f32 [N,32] @ Wt1, scaled by dinv -> B0 f16 [N,128] ----
__global__ __launch_bounds__(256) void k_mfma_l1(const float* __restrict__ X,
        const __half* __restrict__ Wt, const float* __restrict__ dinv,
        __half* __restrict__ Y){
    constexpr int KD = 32, PD = 40, CO = 128;
    __shared__ __half Xs[64 * PD];
    __shared__ __half Ws[CO * PD];
    __shared__ float dvs[64];
    const int r0 = blockIdx.x * 64;
    const int tid = threadIdx.x;
    #pragma unroll
    for (int it = 0; it < 2; ++it){
        int idx = tid + it * 256;
        int row = idx >> 3, q = idx & 7;
        float4 f = ((const float4*)(X + (size_t)(r0 + row) * KD))[q];
        *(__half2*)(Xs + row * PD + q * 4)     = __floats2half2_rn(f.x, f.y);
        *(__half2*)(Xs + row * PD + q * 4 + 2) = __floats2half2_rn(f.z, f.w);
    }
    #pragma unroll
    for (int it = 0; it < 2; ++it){
        int idx = tid + it * 256;
        int row = idx >> 2, q = idx & 3;
        uint4 u = ((const uint4*)(Wt + (size_t)row * KD))[q];
        *(uint4*)(Ws + row * PD + q * 8) = u;
    }
    if (tid < 64) dvs[tid] = dinv[r0 + tid];
    __syncthreads();
    const int wv = tid >> 6, lane = tid & 63, lr = lane & 15, lh = lane >> 4;
    const int rw = (wv >> 1) * 32;
    const int cw = (wv & 1) * 64;
    floatx4 acc[2][4];
    #pragma unroll
    for (int t = 0; t < 2; ++t)
        #pragma unroll
        for (int ct = 0; ct < 4; ++ct) acc[t][ct] = (floatx4){0.f, 0.f, 0.f, 0.f};
    int kb = lh * 8;
    half8 a0 = *(const half8*)(Xs + (rw + lr) * PD + kb);
    half8 a1 = *(const half8*)(Xs + (rw + 16 + lr) * PD + kb);
    #pragma unroll
    for (int ct = 0; ct < 4; ++ct){
        half8 b = *(const half8*)(Ws + (cw + ct * 16 + lr) * PD + kb);
        acc[0][ct] = __builtin_amdgcn_mfma_f32_16x16x32_f16(a0, b, acc[0][ct], 0, 0, 0);
        acc[1][ct] = __builtin_amdgcn_mfma_f32_16x16x32_f16(a1, b, acc[1][ct], 0, 0, 0);
    }
    #pragma unroll
    for (int ct = 0; ct < 4; ++ct){
        int col = cw + ct * 16 + lr;
        #pragma unroll
        for (int t = 0; t < 2; ++t)
            #pragma unroll
            for (int reg = 0; reg < 4; ++reg){
                int rl = rw + t * 16 + lh * 4 + reg;
                Y[(size_t)(r0 + rl) * CO + col] = __float2half(acc[t][ct][reg] * dvs[rl]);
            }
    }
}

// ---------------- fused gather + bias + selu: 16 thr/node x uint2 (8B), ILP-8 ----------------
// Strides/offsets in uint2 (4-half) units. 4 node-streams per wave -> 2x memory parallelism.
#define GACC(v) { float2 g0_ = __half22float2(*(const __half2*)&(v).x); \
                  float2 g1_ = __half22float2(*(const __half2*)&(v).y); \
                  a0 += g0_.x; a1 += g0_.y; a2 += g1_.x; a3 += g1_.y; }
__global__ __launch_bounds__(256) void k_gather64(const int* __restrict__ indptr,
        const int* __restrict__ esrc, const float* __restrict__ dinv,
        const uint2* __restrict__ Xs, int xsu, int xoff,
        const float* __restrict__ bias, int boff,
        uint2* __restrict__ Yo, int ysu){
    int t = blockIdx.x * blockDim.x + threadIdx.x;
    int node = t >> 4;
    if (node >= NNODES) return;
    int c4 = t & 15;
    float dn = dinv[node];
    int beg = indptr[node], end = indptr[node + 1];
    const uint2* xp = Xs + xoff + c4;
    uint2 u = xp[(size_t)node * xsu];
    float2 s0 = __half22float2(*(const __half2*)&u.x);
    float2 s1 = __half22float2(*(const __half2*)&u.y);
    float a0 = s0.x, a1 = s0.y, a2 = s1.x, a3 = s1.y;
    int j = beg;
    for (; j + 8 <= end; j += 8){
        int n0 = esrc[j],   n1 = esrc[j+1], n2 = esrc[j+2], n3 = esrc[j+3];
        int n4 = esrc[j+4], n5 = esrc[j+5], n6 = esrc[j+6], n7 = esrc[j+7];
        uint2 v0 = xp[(size_t)n0 * xsu];
        uint2 v1 = xp[(size_t)n1 * xsu];
        uint2 v2 = xp[(size_t)n2 * xsu];
        uint2 v3 = xp[(size_t)n3 * xsu];
        uint2 v4 = xp[(size_t)n4 * xsu];
        uint2 v5 = xp[(size_t)n5 * xsu];
        uint2 v6 = xp[(size_t)n6 * xsu];
        uint2 v7 = xp[(size_t)n7 * xsu];
        GACC(v0) GACC(v1) GACC(v2) GACC(v3)
        GACC(v4) GACC(v5) GACC(v6) GACC(v7)
    }
    for (; j + 4 <= end; j += 4){
        int n0 = esrc[j], n1 = esrc[j+1], n2 = esrc[j+2], n3 = esrc[j+3];
        uint2 v0 = xp[(size_t)n0 * xsu];
        uint2 v1 = xp[(size_t)n1 * xsu];
        uint2 v2 = xp[(size_t)n2 * xsu];
        uint2 v3 = xp[(size_t)n3 * xsu];
        GACC(v0) GACC(v1) GACC(v2) GACC(v3)
    }
    for (; j < end; ++j){
        uint2 v = xp[(size_t)esrc[j] * xsu];
        GACC(v)
    }
    int ch = boff + 4 * c4;
    a0 = selu_f(a0 * dn + bias[ch + 0]);
    a1 = selu_f(a1 * dn + bias[ch + 1]);
    a2 = selu_f(a2 * dn + bias[ch + 2]);
    a3 = selu_f(a3 * dn + bias[ch + 3]);
    uint2 o;
    *(__half2*)&o.x = __floats2half2_rn(a0, a1);
    *(__half2*)&o.y = __floats2half2_rn(a2, a3);
    Yo[(size_t)node * ysu + c4] = o;
}

// ---------------- per-graph masked-node selection + shuffle ----------------
__global__ void k_qnode(const float* __restrict__ x, const int* __restrict__ shuf,
                        int* __restrict__ qnode){
    int b = blockIdx.x;
    int lane = threadIdx.x;   // 64
    __shared__ int list[MAXN];
    int localIdx[16];
    int cnt = 0;
    #pragma unroll
    for (int j = 0; j < 16; ++j){
        int node = lane * 16 + j;
        float m = x[(size_t)(b * NNPG + node) * INCH + (INCH - 3)];
        if (m > 0.5f){ if (cnt < 16) localIdx[cnt] = node; cnt++; }
    }
    int pref = cnt;
    #pragma unroll
    for (int off = 1; off < 64; off <<= 1){
        int v = __shfl_up(pref, off);
        if (lane >= off) pref += v;
    }
    pref -= cnt;
    for (int t = 0; t < cnt; ++t){
        int pos = pref + t;
        if (pos < MAXN) list[pos] = localIdx[t];
    }
    __syncthreads();
    if (lane < MAXN){
        int sidx = shuf[b * MAXN + lane];
        qnode[b * MAXN + lane] = b * NNPG + list[sidx];
    }
}

// ---------------- Q = (h2[qnode] @ Wq + bq) / sqrt(H); h2 split in B1/B0 ----------------
__global__ __launch_bounds__(128) void k_qgemm(const __half* __restrict__ hLo,
        const __half* __restrict__ hHi, const int* __restrict__ qnode,
        const float* __restrict__ Wq, const float* __restrict__ bq, float* __restrict__ Q){
    __shared__ float hs[HD];
    int row = blockIdx.x;
    int c = threadIdx.x;
    int node = qnode[row];
    if (c < 64) hs[c] = __half2float(hLo[(size_t)node * 64 + c]);
    else        hs[c] = __half2float(hHi[(size_t)node * 128 + (c - 64)]);
    __syncthreads();
    float acc = bq[c];
    for (int k = 0; k < HD; ++k) acc += hs[k] * Wq[k * HD + c];
    Q[row * HD + c] = acc * 0.08838834764831845f;
}

// ---------------- softmax over k for each (b,i); scores_t [b][k][8] in-place ----------------
__global__ __launch_bounds__(256) void k_softmax2(float* __restrict__ st){
    int b = blockIdx.x, tid = threadIdx.x;
    int wv = tid >> 6, lane = tid & 63;
    float* base = st + (size_t)b * NNPG * MAXN;
    float v[4][MAXN];
    #pragma unroll
    for (int r = 0; r < 4; ++r){
        int k = tid + r * 256;
        float4 a0 = ((const float4*)(base + k * MAXN))[0];
        float4 a1 = ((const float4*)(base + k * MAXN))[1];
        v[r][0]=a0.x; v[r][1]=a0.y; v[r][2]=a0.z; v[r][3]=a0.w;
        v[r][4]=a1.x; v[r][5]=a1.y; v[r][6]=a1.z; v[r][7]=a1.w;
    }
    float m[MAXN];
    #pragma unroll
    for (int i = 0; i < MAXN; ++i)
        m[i] = fmaxf(fmaxf(v[0][i], v[1][i]), fmaxf(v[2][i], v[3][i]));
    #pragma unroll
    for (int off = 32; off; off >>= 1)
        #pragma unroll
        for (int i = 0; i < MAXN; ++i) m[i] = fmaxf(m[i], __shfl_xor(m[i], off));
    __shared__ float red[2][4][MAXN];
    if (lane == 0)
        #pragma unroll
        for (int i = 0; i < MAXN; ++i) red[0][wv][i] = m[i];
    __syncthreads();
    #pragma unroll
    for (int i = 0; i < MAXN; ++i)
        m[i] = fmaxf(fmaxf(red[0][0][i], red[0][1][i]), fmaxf(red[0][2][i], red[0][3][i]));
    float s[MAXN];
    #pragma unroll
    for (int i = 0; i < MAXN; ++i) s[i] = 0.f;
    #pragma unroll
    for (int r = 0; r < 4; ++r)
        #pragma unroll
        for (int i = 0; i < MAXN; ++i){
            v[r][i] = expf(v[r][i] - m[i]);
            s[i] += v[r][i];
        }
    #pragma unroll
    for (int off = 32; off; off >>= 1)
        #pragma unroll
        for (int i = 0; i < MAXN; ++i) s[i] += __shfl_xor(s[i], off);
    if (lane == 0)
        #pragma unroll
        for (int i = 0; i < MAXN; ++i) red[1][wv][i] = s[i];
    __syncthreads();
    #pragma unroll
    for (int i = 0; i < MAXN; ++i){
        float tot = red[1][0][i] + red[1][1][i] + red[1][2][i] + red[1][3][i];
        s[i] = 1.0f / tot;
    }
    #pragma unroll
    for (int r = 0; r < 4; ++r){
        int k = tid + r * 256;
        float4 a0 = make_float4(v[r][0]*s[0], v[r][1]*s[1], v[r][2]*s[2], v[r][3]*s[3]);
        float4 a1 = make_float4(v[r][4]*s[4], v[r][5]*s[5], v[r][6]*s[6], v[r][7]*s[7]);
        ((float4*)(base + k * MAXN))[0] = a0;
        ((float4*)(base + k * MAXN))[1] = a1;
    }
}

// ---------------- tail: Wo+bo+selu then Wfc+bfc -> out[b][8] ----------------
__global__ __launch_bounds__(256) void k_tail(const float* __restrict__ pvout,
        const float* __restrict__ Wo, const float* __restrict__ bo,
        const float* __restrict__ Wfc, const float* __restrict__ bfc,
        float* __restrict__ out){
    int b = blockIdx.x;
    int tid = threadIdx.x;
    __shared__ float pv[MAXN * HD];
    __shared__ float sol[MAXN * HD];
    __shared__ float red[64];
    for (int idx = tid; idx < MAXN * HD / 4; idx += 256)
        ((float4*)pv)[idx] = ((const float4*)(pvout + (size_t)b * MAXN * HD))[idx];
    __syncthreads();
    int c = tid & 127;
    int grp = tid >> 7;
    float bb = bo[c];
    float acc[4];
    #pragma unroll
    for (int j = 0; j < 4; ++j) acc[j] = bb;
    for (int k = 0; k < HD; ++k){
        float w = Wo[k * HD + c];
        #pragma unroll
        for (int j = 0; j < 4; ++j) acc[j] += pv[(grp*4 + j) * HD + k] * w;
    }
    #pragma unroll
    for (int j = 0; j < 4; ++j) sol[(grp*4 + j) * HD + c] = selu_f(acc[j]);
    __syncthreads();
    if (tid < 64){
        int j = tid & 7;
        int part = tid >> 3;
        float p = 0.f;
        for (int m = part * 128; m < part * 128 + 128; ++m) p += sol[m] * Wfc[m * MAXN + j];
        red[tid] = p;
    }
    __syncthreads();
    if (tid < MAXN){
        float s = bfc[tid];
        #pragma unroll
        for (int part = 0; part < 8; ++part) s += red[part * 8 + tid];
        out[b * MAXN + tid] = s;
    }
}

extern "C" void kernel_launch(void* const* d_in, const int* in_sizes, int n_in,
                              void* d_out, int out_size, void* d_ws, size_t ws_size,
                              hipStream_t stream) {
    const float* x    = (const float*)d_in[0];
    const int*   edge = (const int*)d_in[1];
    const int*   shuf = (const int*)d_in[2];
    const float* W1   = (const float*)d_in[3];
    const float* b1   = (const float*)d_in[4];
    const float* W2   = (const float*)d_in[5];
    const float* b2   = (const float*)d_in[6];
    const float* Wq   = (const float*)d_in[7];
    const float* bq   = (const float*)d_in[8];
    const float* Wk   = (const float*)d_in[9];
    const float* bk   = (const float*)d_in[10];
    const float* Wv   = (const float*)d_in[11];
    const float* bv   = (const float*)d_in[12];
    const float* Wo   = (const float*)d_in[13];
    const float* bo   = (const float*)d_in[14];
    const float* Wfc  = (const float*)d_in[15];
    const float* bfc  = (const float*)d_in[16];
    float* out = (float*)d_out;

    // workspace layout — ~107.1 MiB
    char* w = (char*)d_ws;
    __half* B0    = (__half*)w;  w += (size_t)NNODES * HD * sizeof(__half);    // 64 MiB
    __half* B1    = (__half*)w;  w += (size_t)NNODES * 64 * sizeof(__half);    // 32 MiB (ecur during CSR build)
    float*  R1    = (float*)w;   w += (size_t)NNODES * sizeof(float);          // 1 MiB: dinv (pvout after)
    int*    R2    = (int*)w;     w += (size_t)NNODES * sizeof(int);            // 1 MiB: deg (Qb after)
    int*    indptr= (int*)w;     w += ((size_t)NNODES + 64) * sizeof(int);
    int*    bsum  = (int*)w;     w += 1024;
    int*    qnode = (int*)w;     w += 8192;
    __half* Wt1   = (__half*)w;  w += 128 * INCH * sizeof(__half);
    __half* Wt2   = (__half*)w;  w += 128 * HD * sizeof(__half);
    __half* Wtk   = (__half*)w;  w += 128 * HD * sizeof(__half);
    __half* Wtv   = (__half*)w;  w += 128 * HD * sizeof(__half);
    char*   U     = w;           w += (size_t)NGRAPH * MAXN * NNPG * sizeof(float); // 8 MiB
    size_t need = (size_t)(w - (char*)d_ws);
    if (ws_size < need) return;

    float* dinv  = R1;
    float* pvout = R1;            // reused after layer-2 gathers
    int*   degb  = R2;
    float* Qb    = (float*)R2;    // reused after CSR build
    int*   ecur  = (int*)B1;      // per-edge rank, lives in B1 during CSR build
    int*   esrc  = (int*)U;       // GNN phase
    float* st    = (float*)U;     // attention phase

    const int* srcp = edge;
    const int* dstp = edge + NEDGE;

    // ---- CSR build (atomic only in deg pass; fill is atomic-free) ----
    hipMemsetAsync(degb, 0, NNODES * sizeof(int), stream);
    k_deg<<<NEDGE / 256, 256, 0, stream>>>(dstp, degb, ecur);
    k_dinv<<<NNODES / 256, 256, 0, stream>>>(degb, dinv);
    k_scan1<<<256, 256, 0, stream>>>(degb, indptr, bsum);
    k_scan2<<<1, 256, 0, stream>>>(bsum);
    k_scan3<<<256, 256, 0, stream>>>(indptr, bsum);
    k_fill<<<NEDGE / 256, 256, 0, stream>>>(srcp, dstp, indptr, ecur, esrc);

    // ---- weight prep ----
    k_wprep<<<(128 * INCH) / 256, 256, 0, stream>>>(W1, Wt1, INCH);
    k_wprep<<<(128 * HD) / 256, 256, 0, stream>>>(W2, Wt2, HD);
    k_wprep<<<(128 * HD) / 256, 256, 0, stream>>>(Wk, Wtk, HD);
    k_wprep<<<(128 * HD) / 256, 256, 0, stream>>>(Wv, Wtv, HD);

    const int gBlocks = (NNODES * 16) / 256;   // gather grid (16 thr/node)

    // ---- layer 1: scaled xw1 full in B0; gather h0->B1, h1->B0[:,0:64] ----
    k_mfma_l1<<<NNODES / 64, 256, 0, stream>>>(x, Wt1, dinv, B0);
    k_gather64<<<gBlocks, 256, 0, stream>>>(indptr, esrc, dinv,
            (const uint2*)B0, 32, 0,  b1, 0,  (uint2*)B1, 16);
    k_gather64<<<gBlocks, 256, 0, stream>>>(indptr, esrc, dinv,
            (const uint2*)B0, 32, 16, b1, 64, (uint2*)B0, 32);
    // ---- layer 2: split-A GEMM -> scaled xw2 full in B0 (in-place); gathers ----
    k_mfma_sp<<<NNODES / 64, 256, 0, stream>>>(B1, B0, Wt2, dinv, B0);
    k_gather64<<<gBlocks, 256, 0, stream>>>(indptr, esrc, dinv,
            (const uint2*)B0, 32, 0,  b2, 0,  (uint2*)B1, 16);
    k_gather64<<<gBlocks, 256, 0, stream>>>(indptr, esrc, dinv,
            (const uint2*)B0, 32, 16, b2, 64, (uint2*)B0, 32);
    // h2: cols 0-63 in B1 (stride 64), cols 64-127 in B0[:,0:64] (stride 128)

    // ---- attention ----
    k_qnode<<<NGRAPH, 64, 0, stream>>>(x, shuf, qnode);
    k_qgemm<<<NGRAPH * MAXN, 128, 0, stream>>>(B1, B0, qnode, Wq, bq, Qb);

    // fused K-GEMM + scores (K lives only in LDS)
    k_kscores<<<NNODES / 64, 256, 0, stream>>>(B1, B0, Wtk, bk, Qb, st);
    k_softmax2<<<NGRAPH, 256, 0, stream>>>(st);
    // fused V-GEMM + partial PV -> Opart in dead B0[:,64:128] region
    k_vpv<<<NNODES / 64, 256, 0, stream>>>(B1, B0, Wtv, bv, st, B0);
    k_oreduce<<<(NGRAPH * MAXN * HD) / 256, 256, 0, stream>>>(B0, pvout);

    k_tail<<<NGRAPH, 256, 0, stream>>>(pvout, Wo, bo, Wfc, bfc, out);
}